// Round 2
// baseline (395.699 us; speedup 1.0000x reference)
//
#include <hip/hip_runtime.h>
#include <hip/hip_bf16.h>

#define BLOCK   1024    // 16 waves = two independent 8-wave sample-groups (halves)
#define NSAMP   16      // samples per half; block covers 32 samples
#define HDIM    128
#define DDIM    16
#define NOBJ    6
#define NSLOT   14

typedef __attribute__((ext_vector_type(8))) short bf16x8;
typedef __attribute__((ext_vector_type(4))) float f32x4;

constexpr int pc6(int m)  { int c = 0; for (int i = 0; i < 6; ++i) c += (m >> i) & 1; return c; }
constexpr int msb6(int m) { int b = -1; for (int i = 0; i < 6; ++i) if (m & (1 << i)) b = i; return b; }

// Compile-time BFS plan, 14-slot allocator with multi-phase recycling (verified R11/R13).
struct PNode { int jo, ps, sl; bool bar; };
struct Plan2 { PNode nd[63]; int lvlStart[8]; };
constexpr Plan2 make_plan2() {
    Plan2 P{};
    int slotOf[64] = {};
    bool busy[NSLOT] = {};
    int k = 0;
    for (int d = 1; d <= 6; ++d) {
        P.lvlStart[d] = k;
        for (int M = 1; M < 64; ++M) {               // leaves (msb==5): no slot
            if (pc6(M) != d || msb6(M) != 5) continue;
            P.nd[k].jo = 5;
            P.nd[k].ps = (d == 1) ? -1 : slotOf[M & ~(1 << 5)];
            P.nd[k].sl = -1;
            P.nd[k].bar = false;
            ++k;
        }
        int pend[20] = {}; int np = 0;
        for (int M = 1; M < 64; ++M)
            if (pc6(M) == d && msb6(M) < 5) pend[np++] = M;
        int key[20] = {};
        for (int i = 0; i < np; ++i) {
            if (d == 1) { key[i] = 0; continue; }
            const int par = pend[i] & ~(1 << msb6(pend[i]));
            int c2 = 0;
            for (int j2 = 0; j2 < np; ++j2)
                if ((pend[j2] & ~(1 << msb6(pend[j2]))) == par) ++c2;
            key[i] = c2;
        }
        for (int a = 0; a < np; ++a)
            for (int b2 = a + 1; b2 < np; ++b2)
                if (key[b2] < key[a]) {
                    int tm = key[a]; key[a] = key[b2]; key[b2] = tm;
                    tm = pend[a]; pend[a] = pend[b2]; pend[b2] = tm;
                }
        bool placed[20] = {};
        int nplaced = 0;
        bool firstPhase = true;
        while (nplaced < np) {
            bool needBar = !firstPhase;
            bool any = false;
            for (int i = 0; i < np; ++i) {
                if (placed[i]) continue;
                int fs = -1;
                for (int s = 0; s < NSLOT; ++s) if (!busy[s]) { fs = s; break; }
                if (fs < 0) break;
                const int M = pend[i]; const int hi = msb6(M);
                busy[fs] = true; slotOf[M] = fs;
                P.nd[k].jo = hi;
                P.nd[k].ps = (d == 1) ? -1 : slotOf[M & ~(1 << hi)];
                P.nd[k].sl = fs;
                P.nd[k].bar = needBar; needBar = false;
                ++k; placed[i] = true; ++nplaced; any = true;
            }
            firstPhase = false;
            if (nplaced < np) {
                if (!any) break;
                for (int M = 1; M < 64; ++M) {
                    if (pc6(M) != d - 1 || msb6(M) >= 5) continue;
                    bool allp = true;
                    for (int i = 0; i < np; ++i)
                        if (!placed[i] &&
                            ((pend[i] & ~(1 << msb6(pend[i]))) == M)) allp = false;
                    if (allp) busy[slotOf[M]] = false;
                }
            }
        }
        for (int s = 0; s < NSLOT; ++s) busy[s] = false;
        for (int M = 1; M < 64; ++M)
            if (pc6(M) == d && msb6(M) < 5) busy[slotOf[M]] = true;
    }
    P.lvlStart[7] = k;
    return P;
}
constexpr Plan2 PL2 = make_plan2();
static_assert(PL2.lvlStart[7] == 63, "plan must cover all 63 nodes");

#define LOG2E   1.44269504f
#define TWOL2E  2.88539008f
#define SLOT_SH 2048            // shorts per slot (4 KB), h pool
#define HALF_HS (NSLOT * SLOT_SH)          // 28672 shorts = 56 KB
#define HALF_XB (NOBJ * 4 * NSAMP * 8)     // 3072 shorts  = 6 KB

__device__ __forceinline__ unsigned short f2bf(float x) {
    union { float f; unsigned int u; } a; a.f = x;
    unsigned int r = (a.u + 0x7FFFu + ((a.u >> 16) & 1u)) >> 16;
    return (unsigned short)r;
}
__device__ __forceinline__ unsigned pk2(float a, float b) {
    union { __hip_bfloat162 h; unsigned u; } z;
    z.h = __float22bfloat162_rn(float2{a, b});
    return z.u;
}
__device__ __forceinline__ float bflo(unsigned p) {
    union { unsigned u; float f; } a; a.u = p << 16; return a.f;
}
__device__ __forceinline__ float bfhi(unsigned p) {
    union { unsigned u; float f; } a; a.u = p & 0xFFFF0000u; return a.f;
}

// h pool (per half): hs[half][((slot*16 + kslot)*NSAMP + n)*8 + j]
//   B-frag chunk q, lane (quad,m16): kslot = q*4+quad -> 16B-aligned ds_read_b128
//   wave w8 writes ch = w8*16+quad*4+r at kslot = w8*2+(quad>>1), j = (quad&1)*4+r
// c state: LANE-PRIVATE (producer lane == consumer lane), in registers
//   c_reg[NSLOT] (uint2 = 4x bf16), statically indexed after full unroll.
// x-chunk A-frags (wf[g][4]) live in a shared LDS table wfx (32 KB, shared by
//   both halves) to cut persistent VGPRs from 80 to 64 -> fits the 128 cap
//   that __launch_bounds__(1024) imposes (16 waves = 4/SIMD).

__global__ __launch_bounds__(BLOCK)
void subset_lstm_skew_kernel(
    const float* __restrict__ x_input,
    const float* __restrict__ W_ih,
    const float* __restrict__ W_hh,
    const float* __restrict__ b_ih,
    const float* __restrict__ b_hh,
    const float* __restrict__ fc1_W,
    const float* __restrict__ fc1_b,
    const float* __restrict__ fc2_W,
    const float* __restrict__ fc2_b,
    float* __restrict__ out)
{
    __shared__ __align__(16) unsigned short hs [2 * HALF_HS];       // 112 KB
    __shared__ __align__(16) unsigned short xb [2 * HALF_XB];       // 12 KB
    __shared__ __align__(16) unsigned short wfx[8 * 4 * 64 * 8];    // 32 KB
    float* s_maxh  = (float*)hs;                 // 16 KB (post-LSTM alias)
    float* s_fc1   = (float*)(hs + 8192);        // 32 KB (post-LSTM alias)
    float* s_logit = (float*)xb;

    const int t      = threadIdx.x;
    const int w      = t >> 6;
    const int half   = w >> 3;          // sample-group 0/1
    const int w8     = w & 7;
    const int lane   = t & 63;
    const int quad   = lane >> 4;
    const int m16    = lane & 15;
    const int s_blk  = blockIdx.x * (2 * NSAMP);

    unsigned short* const hsH = hs + half * HALF_HS;
    const unsigned short* const xbH = xb + half * HALF_XB;

    // ---- x B-chunks per half: xb[h][obj][q][n][j]; q2 j0 = 1.0 (bias), q3 zero ----
    for (int idx = t; idx < 2 * HALF_XB; idx += BLOCK) {
        const int hI  = idx >= HALF_XB;
        const int rem = idx - hI * HALF_XB;
        const int j = rem & 7, n = (rem >> 3) & 15, q = (rem >> 7) & 3, obj = rem >> 9;
        float v;
        if (q < 2) v = x_input[(s_blk + hI * NSAMP + n) * (NOBJ * DDIM) + obj * DDIM + q * 8 + j];
        else       v = (q == 2 && j == 0) ? 1.0f : 0.0f;
        xb[idx] = f2bf(v);
    }

    // ---- persistent A-frags wf[gate][chunk0..3], PRE-SCALED; x-chunk -> wfx LDS ----
    bf16x8 wf[4][4];
    #pragma unroll
    for (int g = 0; g < 4; ++g) {
        const float sc = (g == 2) ? TWOL2E : -LOG2E;
        const int grow = g * HDIM + w8 * 16 + m16;
        const float* whr = W_hh + grow * HDIM;
        const float* wir = W_ih + grow * DDIM;
        #pragma unroll
        for (int q = 0; q < 4; ++q) {
            union { unsigned short u[8]; bf16x8 v; } pk;
            #pragma unroll
            for (int j = 0; j < 8; ++j)
                pk.u[j] = f2bf(sc * whr[q * 32 + quad * 8 + j]);
            wf[g][q] = pk.v;
        }
        if (half == 0) {    // shared x-chunk table, identical for both halves
            union { unsigned short u[8]; bf16x8 v; } pk;
            #pragma unroll
            for (int j = 0; j < 8; ++j) {
                float v = 0.0f;
                if (quad < 2) v = sc * wir[quad * 8 + j];
                else if (quad == 2 && j == 0) v = sc * (b_ih[grow] + b_hh[grow]);
                pk.u[j] = f2bf(v);
            }
            *(bf16x8*)&wfx[((w8 * 4 + g) * 64 + lane) * 8] = pk.v;
        }
    }

    float mh[4] = {-1e30f, -1e30f, -1e30f, -1e30f};
    const int kslot = w8 * 2 + (quad >> 1);
    uint2 c_reg[NSLOT];   // lane-private c state, 4x bf16 per slot, static idx

    // GEMM for node (jo, ps)
    auto mfma_node = [&](f32x4 (&acc)[4], int jo, int ps) {
        {
            const bf16x8 bfx = *(const bf16x8*)&xbH[((jo * 4 + quad) * NSAMP + m16) * 8];
            #pragma unroll
            for (int g = 0; g < 4; ++g) {
                const bf16x8 ax = *(const bf16x8*)&wfx[((w8 * 4 + g) * 64 + lane) * 8];
                acc[g] = __builtin_amdgcn_mfma_f32_16x16x32_bf16(
                    ax, bfx, f32x4{0.f, 0.f, 0.f, 0.f}, 0, 0, 0);
            }
        }
        if (ps >= 0) {
            #pragma unroll
            for (int q = 0; q < 4; ++q) {
                const bf16x8 bh = *(const bf16x8*)
                    &hsH[((ps * 16 + q * 4 + quad) * NSAMP + m16) * 8];
                #pragma unroll
                for (int g = 0; g < 4; ++g)
                    acc[g] = __builtin_amdgcn_mfma_f32_16x16x32_bf16(
                        wf[g][q], bh, acc[g], 0, 0, 0);
            }
        }
    };

    // fused pointwise (verified R9-R13); c from/to registers
    auto pointwise_node = [&](const f32x4 (&acc)[4], int ps, int sl) {
        uint2 cpk;
        if (ps >= 0) cpk = c_reg[ps];
        else         { cpk.x = 0u; cpk.y = 0u; }
        float cn4[4], hn4[4];
        #pragma unroll
        for (int r = 0; r < 4; ++r) {
            const unsigned p = (r < 2) ? cpk.x : cpk.y;
            const float cprev = (r & 1) ? bfhi(p) : bflo(p);
            const float u  = 1.0f + __builtin_amdgcn_exp2f(acc[0][r]);
            const float q  = 1.0f + __builtin_amdgcn_exp2f(acc[1][r]);
            const float v  = 1.0f + __builtin_amdgcn_exp2f(acc[2][r]);
            const float qo = 1.0f + __builtin_amdgcn_exp2f(acc[3][r]);
            const float uv  = u * v;
            const float num = fmaf(q, v - 2.0f, cprev * uv);
            const float cn  = num * __builtin_amdgcn_rcpf(q * uv);
            const float wt  = 1.0f + __builtin_amdgcn_exp2f(TWOL2E * cn);
            const float h   = (wt - 2.0f) * __builtin_amdgcn_rcpf(qo * wt);
            cn4[r] = cn; hn4[r] = h;
            mh[r] = fmaxf(mh[r], h);
        }
        if (sl >= 0) {
            c_reg[sl].x = pk2(cn4[0], cn4[1]);
            c_reg[sl].y = pk2(cn4[2], cn4[3]);
            uint2 hw; hw.x = pk2(hn4[0], hn4[1]); hw.y = pk2(hn4[2], hn4[3]);
            *(uint2*)&hsH[((sl * 16 + kslot) * NSAMP + m16) * 8 + (quad & 1) * 4] = hw;
        }
    };

    #pragma unroll
    for (int d = 1; d <= 6; ++d) {
        __syncthreads();
        const int kBeg = PL2.lvlStart[d];
        const int kEnd = PL2.lvlStart[d + 1];
        #pragma unroll
        for (int k = kBeg; k < kEnd; ++k) {
            if (PL2.nd[k].bar) __syncthreads();   // recycle barrier (constexpr)
            f32x4 acc[4];
            mfma_node(acc, PL2.nd[k].jo, PL2.nd[k].ps);
            pointwise_node(acc, PL2.nd[k].ps, PL2.nd[k].sl);
        }
    }

    __syncthreads();   // pools dead; reuse hs for epilogue
    {
        float4 v; v.x = mh[0]; v.y = mh[1]; v.z = mh[2]; v.w = mh[3];
        *(float4*)&s_maxh[(half * NSAMP + m16) * HDIM + w8 * 16 + quad * 4] = v;
    }
    __syncthreads();

    // ---- FC1: f = t&255, sample group t>>8 (4 groups x 8 samples = 32) ----
    {
        const int f  = t & 255;
        const int sg = t >> 8;
        float a1[8];
        #pragma unroll
        for (int s = 0; s < 8; ++s) a1[s] = fc1_b[f];
        for (int k4 = 0; k4 < HDIM / 4; ++k4) {
            const float4 wv = *(const float4*)&fc1_W[f * HDIM + k4 * 4];
            #pragma unroll
            for (int s = 0; s < 8; ++s) {
                const float4 h4 = *(const float4*)&s_maxh[(sg * 8 + s) * HDIM + k4 * 4];
                a1[s] += wv.x * h4.x + wv.y * h4.y + wv.z * h4.z + wv.w * h4.w;
            }
        }
        #pragma unroll
        for (int s = 0; s < 8; ++s)
            s_fc1[(sg * 8 + s) * 256 + f] = fmaxf(a1[s], 0.0f);
    }
    __syncthreads();

    if (t < 2 * NSAMP * 10) {
        const int s = t / 10, a = t % 10;
        float acc2 = fc2_b[a];
        for (int f4 = 0; f4 < 256 / 4; ++f4) {
            const float4 wv = *(const float4*)&fc2_W[a * 256 + f4 * 4];
            const float4 v  = *(const float4*)&s_fc1[s * 256 + f4 * 4];
            acc2 += wv.x * v.x + wv.y * v.y + wv.z * v.z + wv.w * v.w;
        }
        s_logit[s * 10 + a] = acc2;
    }
    __syncthreads();

    if (t < 2 * NSAMP) {
        float m = -1e30f;
        #pragma unroll
        for (int a = 0; a < 10; ++a) m = fmaxf(m, s_logit[t * 10 + a]);
        float sum = 0.0f;
        #pragma unroll
        for (int a = 0; a < 10; ++a) sum += __expf(s_logit[t * 10 + a] - m);
        const float lse = m + __logf(sum);
        #pragma unroll
        for (int a = 0; a < 10; ++a)
            out[(s_blk + t) * 10 + a] = s_logit[t * 10 + a] - lse;
    }
}

extern "C" void kernel_launch(void* const* d_in, const int* in_sizes, int n_in,
                              void* d_out, int out_size, void* d_ws, size_t ws_size,
                              hipStream_t stream)
{
    (void)d_ws; (void)ws_size; (void)n_in; (void)out_size;

    const float* x   = (const float*)d_in[0];
    const float* Wih = (const float*)d_in[1];
    const float* Whh = (const float*)d_in[2];
    const float* bih = (const float*)d_in[3];
    const float* bhh = (const float*)d_in[4];
    const float* f1w = (const float*)d_in[5];
    const float* f1b = (const float*)d_in[6];
    const float* f2w = (const float*)d_in[7];
    const float* f2b = (const float*)d_in[8];

    const int mb = in_sizes[0] / (NOBJ * DDIM);   // 8192
    dim3 grid(mb / (2 * NSAMP)), block(BLOCK);    // 256 blocks = 1 per CU
    subset_lstm_skew_kernel<<<grid, block, 0, stream>>>(
        x, Wih, Whh, bih, bhh, f1w, f1b, f2w, f2b, (float*)d_out);
}

// Round 3
// 368.928 us; speedup vs baseline: 1.0726x; 1.0726x over previous
//
#include <hip/hip_runtime.h>
#include <hip/hip_bf16.h>

#define BLOCK   512     // 8 waves; wave w owns channels w*16..w*16+15, all 4 gates
#define NSAMP   16
#define HDIM    128
#define DDIM    16
#define NOBJ    6
#define NSLOT   14

typedef __attribute__((ext_vector_type(8))) short bf16x8;
typedef __attribute__((ext_vector_type(4))) float f32x4;

constexpr int pc6(int m)  { int c = 0; for (int i = 0; i < 6; ++i) c += (m >> i) & 1; return c; }
constexpr int msb6(int m) { int b = -1; for (int i = 0; i < 6; ++i) if (m & (1 << i)) b = i; return b; }

// Compile-time BFS plan, 14-slot allocator with multi-phase recycling (verified R11/R13).
struct PNode { int jo, ps, sl; bool bar; };
struct Plan2 { PNode nd[63]; int lvlStart[8]; };
constexpr Plan2 make_plan2() {
    Plan2 P{};
    int slotOf[64] = {};
    bool busy[NSLOT] = {};
    int k = 0;
    for (int d = 1; d <= 6; ++d) {
        P.lvlStart[d] = k;
        for (int M = 1; M < 64; ++M) {               // leaves (msb==5): no slot
            if (pc6(M) != d || msb6(M) != 5) continue;
            P.nd[k].jo = 5;
            P.nd[k].ps = (d == 1) ? -1 : slotOf[M & ~(1 << 5)];
            P.nd[k].sl = -1;
            P.nd[k].bar = false;
            ++k;
        }
        int pend[20] = {}; int np = 0;
        for (int M = 1; M < 64; ++M)
            if (pc6(M) == d && msb6(M) < 5) pend[np++] = M;
        int key[20] = {};
        for (int i = 0; i < np; ++i) {
            if (d == 1) { key[i] = 0; continue; }
            const int par = pend[i] & ~(1 << msb6(pend[i]));
            int c2 = 0;
            for (int j2 = 0; j2 < np; ++j2)
                if ((pend[j2] & ~(1 << msb6(pend[j2]))) == par) ++c2;
            key[i] = c2;
        }
        for (int a = 0; a < np; ++a)
            for (int b2 = a + 1; b2 < np; ++b2)
                if (key[b2] < key[a]) {
                    int tm = key[a]; key[a] = key[b2]; key[b2] = tm;
                    tm = pend[a]; pend[a] = pend[b2]; pend[b2] = tm;
                }
        bool placed[20] = {};
        int nplaced = 0;
        bool firstPhase = true;
        while (nplaced < np) {
            bool needBar = !firstPhase;
            bool any = false;
            for (int i = 0; i < np; ++i) {
                if (placed[i]) continue;
                int fs = -1;
                for (int s = 0; s < NSLOT; ++s) if (!busy[s]) { fs = s; break; }
                if (fs < 0) break;
                const int M = pend[i]; const int hi = msb6(M);
                busy[fs] = true; slotOf[M] = fs;
                P.nd[k].jo = hi;
                P.nd[k].ps = (d == 1) ? -1 : slotOf[M & ~(1 << hi)];
                P.nd[k].sl = fs;
                P.nd[k].bar = needBar; needBar = false;
                ++k; placed[i] = true; ++nplaced; any = true;
            }
            firstPhase = false;
            if (nplaced < np) {
                if (!any) break;
                for (int M = 1; M < 64; ++M) {
                    if (pc6(M) != d - 1 || msb6(M) >= 5) continue;
                    bool allp = true;
                    for (int i = 0; i < np; ++i)
                        if (!placed[i] &&
                            ((pend[i] & ~(1 << msb6(pend[i]))) == M)) allp = false;
                    if (allp) busy[slotOf[M]] = false;
                }
            }
        }
        for (int s = 0; s < NSLOT; ++s) busy[s] = false;
        for (int M = 1; M < 64; ++M)
            if (pc6(M) == d && msb6(M) < 5) busy[slotOf[M]] = true;
    }
    P.lvlStart[7] = k;
    return P;
}
constexpr Plan2 PL2 = make_plan2();
static_assert(PL2.lvlStart[7] == 63, "plan must cover all 63 nodes");

#define LOG2E   1.44269504f
#define TWOL2E  2.88539008f
#define SLOT_SH 2048            // shorts per slot (4 KB), h pool
#define NSLOT_REG 10            // c slots 0..9 in registers
#define NSLOT_LDS 4             // c slots 10..13 in LDS
#define SLOT_C4 2048            // shorts per LDS c slot (512 lanes * 4 shorts)

__device__ __forceinline__ unsigned short f2bf(float x) {
    union { float f; unsigned int u; } a; a.f = x;
    unsigned int r = (a.u + 0x7FFFu + ((a.u >> 16) & 1u)) >> 16;
    return (unsigned short)r;
}
__device__ __forceinline__ unsigned pk2(float a, float b) {
    union { __hip_bfloat162 h; unsigned u; } z;
    z.h = __float22bfloat162_rn(float2{a, b});
    return z.u;
}
__device__ __forceinline__ float bflo(unsigned p) {
    union { unsigned u; float f; } a; a.u = p << 16; return a.f;
}
__device__ __forceinline__ float bfhi(unsigned p) {
    union { unsigned u; float f; } a; a.u = p & 0xFFFF0000u; return a.f;
}

// h pool: hs[((slot*16 + kslot)*NSAMP + n)*8 + j] = h[ch = kslot*8+j][sample n]
//   B-frag chunk q, lane (quad,m16): kslot = q*4+quad -> 16B-aligned ds_read_b128
//   wave w writes ch = w*16+quad*4+r at kslot = w*2+(quad>>1), j = (quad&1)*4+r
// c state: LANE-PRIVATE (producer lane == consumer lane). Slots 0..9 live in
//   registers (uint2, static index after full unroll); slots 10..13 live in a
//   16 KB LDS pool (lane-linear, conflict-free). Split keeps VGPR demand near
//   the 128 cap that waves_per_eu(4,4) imposes (2 blocks/CU, 4 waves/SIMD).
// Allocator model (R0/R1/R2 evidence): targets MAX waves_per_eu, spilling to
//   reach it. Pin (4,4) -> cap 128, no incentive to shrink further.

__global__ __launch_bounds__(BLOCK)
__attribute__((amdgpu_waves_per_eu(4, 4)))
void subset_lstm_skew_kernel(
    const float* __restrict__ x_input,
    const float* __restrict__ W_ih,
    const float* __restrict__ W_hh,
    const float* __restrict__ b_ih,
    const float* __restrict__ b_hh,
    const float* __restrict__ fc1_W,
    const float* __restrict__ fc1_b,
    const float* __restrict__ fc2_W,
    const float* __restrict__ fc2_b,
    float* __restrict__ out)
{
    __shared__ __align__(16) unsigned short hs  [NSLOT * SLOT_SH];        // 56 KB
    __shared__ __align__(16) unsigned short csb4[NSLOT_LDS * SLOT_C4];    // 16 KB
    __shared__ __align__(16) unsigned short xb[NOBJ * 4 * NSAMP * 8];     // 6 KB
    float* s_maxh  = (float*)hs;                 // 8 KB  (post-LSTM alias)
    float* s_fc1   = (float*)(hs + 4096);        // 16 KB (post-LSTM alias)
    float* s_logit = (float*)xb;

    const int t      = threadIdx.x;
    const int w      = t >> 6;
    const int lane   = t & 63;
    const int quad   = lane >> 4;
    const int m16    = lane & 15;
    const int s_base = blockIdx.x * NSAMP;

    // ---- x B-chunks: xb[obj][quad'][n][j]; quad2 j0 = 1.0 (bias lane), quad3 zero ----
    for (int idx = t; idx < NOBJ * 4 * NSAMP * 8; idx += BLOCK) {
        const int j = idx & 7, n = (idx >> 3) & 15, q = (idx >> 7) & 3, obj = idx >> 9;
        float v;
        if (q < 2) v = x_input[(s_base + n) * (NOBJ * DDIM) + obj * DDIM + q * 8 + j];
        else       v = (q == 2 && j == 0) ? 1.0f : 0.0f;
        xb[idx] = f2bf(v);
    }

    // ---- persistent A-frags wf[gate][chunk], PRE-SCALED (verified R8-R13) ----
    bf16x8 wf[4][5];
    #pragma unroll
    for (int g = 0; g < 4; ++g) {
        const float sc = (g == 2) ? TWOL2E : -LOG2E;
        const int grow = g * HDIM + w * 16 + m16;
        const float* whr = W_hh + grow * HDIM;
        const float* wir = W_ih + grow * DDIM;
        #pragma unroll
        for (int q = 0; q < 4; ++q) {
            union { unsigned short u[8]; bf16x8 v; } pk;
            #pragma unroll
            for (int j = 0; j < 8; ++j)
                pk.u[j] = f2bf(sc * whr[q * 32 + quad * 8 + j]);
            wf[g][q] = pk.v;
        }
        {
            union { unsigned short u[8]; bf16x8 v; } pk;
            #pragma unroll
            for (int j = 0; j < 8; ++j) {
                float v = 0.0f;
                if (quad < 2) v = sc * wir[quad * 8 + j];
                else if (quad == 2 && j == 0) v = sc * (b_ih[grow] + b_hh[grow]);
                pk.u[j] = f2bf(v);
            }
            wf[g][4] = pk.v;
        }
    }

    float mh[4] = {-1e30f, -1e30f, -1e30f, -1e30f};
    const int kslot = w * 2 + (quad >> 1);
    uint2 c_reg[NSLOT_REG];   // lane-private c, slots 0..9, static idx
    unsigned short* const c4_lane = &csb4[t * 4];

    // GEMM for node (jo, ps)
    auto mfma_node = [&](f32x4 (&acc)[4], int jo, int ps) {
        {
            const bf16x8 bfx = *(const bf16x8*)&xb[((jo * 4 + quad) * NSAMP + m16) * 8];
            #pragma unroll
            for (int g = 0; g < 4; ++g)
                acc[g] = __builtin_amdgcn_mfma_f32_16x16x32_bf16(
                    wf[g][4], bfx, f32x4{0.f, 0.f, 0.f, 0.f}, 0, 0, 0);
        }
        if (ps >= 0) {
            #pragma unroll
            for (int q = 0; q < 4; ++q) {
                const bf16x8 bh = *(const bf16x8*)
                    &hs[((ps * 16 + q * 4 + quad) * NSAMP + m16) * 8];
                #pragma unroll
                for (int g = 0; g < 4; ++g)
                    acc[g] = __builtin_amdgcn_mfma_f32_16x16x32_bf16(
                        wf[g][q], bh, acc[g], 0, 0, 0);
            }
        }
    };

    // fused pointwise (verified R9-R13); c hybrid reg/LDS, statically selected
    auto pointwise_node = [&](const f32x4 (&acc)[4], int ps, int sl) {
        uint2 cpk;
        if (ps < 0)               { cpk.x = 0u; cpk.y = 0u; }
        else if (ps >= NSLOT_REG) cpk = *(const uint2*)(c4_lane + (ps - NSLOT_REG) * SLOT_C4);
        else                      cpk = c_reg[ps];
        float cn4[4], hn4[4];
        #pragma unroll
        for (int r = 0; r < 4; ++r) {
            const unsigned p = (r < 2) ? cpk.x : cpk.y;
            const float cprev = (r & 1) ? bfhi(p) : bflo(p);
            const float u  = 1.0f + __builtin_amdgcn_exp2f(acc[0][r]);
            const float q  = 1.0f + __builtin_amdgcn_exp2f(acc[1][r]);
            const float v  = 1.0f + __builtin_amdgcn_exp2f(acc[2][r]);
            const float qo = 1.0f + __builtin_amdgcn_exp2f(acc[3][r]);
            const float uv  = u * v;
            const float num = fmaf(q, v - 2.0f, cprev * uv);
            const float cn  = num * __builtin_amdgcn_rcpf(q * uv);
            const float wt  = 1.0f + __builtin_amdgcn_exp2f(TWOL2E * cn);
            const float h   = (wt - 2.0f) * __builtin_amdgcn_rcpf(qo * wt);
            cn4[r] = cn; hn4[r] = h;
            mh[r] = fmaxf(mh[r], h);
        }
        if (sl >= 0) {
            uint2 cw; cw.x = pk2(cn4[0], cn4[1]); cw.y = pk2(cn4[2], cn4[3]);
            if (sl >= NSLOT_REG) *(uint2*)(c4_lane + (sl - NSLOT_REG) * SLOT_C4) = cw;
            else                 c_reg[sl] = cw;
            uint2 hw; hw.x = pk2(hn4[0], hn4[1]); hw.y = pk2(hn4[2], hn4[3]);
            *(uint2*)&hs[((sl * 16 + kslot) * NSAMP + m16) * 8 + (quad & 1) * 4] = hw;
        }
    };

    #pragma unroll
    for (int d = 1; d <= 6; ++d) {
        __syncthreads();
        const int kBeg = PL2.lvlStart[d];
        const int kEnd = PL2.lvlStart[d + 1];
        #pragma unroll
        for (int k = kBeg; k < kEnd; ++k) {
            if (PL2.nd[k].bar) __syncthreads();   // recycle barrier (constexpr)
            f32x4 acc[4];
            mfma_node(acc, PL2.nd[k].jo, PL2.nd[k].ps);
            pointwise_node(acc, PL2.nd[k].ps, PL2.nd[k].sl);
        }
    }

    __syncthreads();   // pools dead; reuse hs for epilogue
    {
        float4 v; v.x = mh[0]; v.y = mh[1]; v.z = mh[2]; v.w = mh[3];
        *(float4*)&s_maxh[m16 * HDIM + w * 16 + quad * 4] = v;
    }
    __syncthreads();

    // ---- FC1: f = t&255, sample half t>>8 (8 samples each) ----
    {
        const int f  = t & 255;
        const int sh = t >> 8;
        float a1[8];
        #pragma unroll
        for (int s = 0; s < 8; ++s) a1[s] = fc1_b[f];
        for (int k4 = 0; k4 < HDIM / 4; ++k4) {
            const float4 wv = *(const float4*)&fc1_W[f * HDIM + k4 * 4];
            #pragma unroll
            for (int s = 0; s < 8; ++s) {
                const float4 h4 = *(const float4*)&s_maxh[(sh * 8 + s) * HDIM + k4 * 4];
                a1[s] += wv.x * h4.x + wv.y * h4.y + wv.z * h4.z + wv.w * h4.w;
            }
        }
        #pragma unroll
        for (int s = 0; s < 8; ++s)
            s_fc1[(sh * 8 + s) * 256 + f] = fmaxf(a1[s], 0.0f);
    }
    __syncthreads();

    if (t < NSAMP * 10) {
        const int s = t / 10, a = t % 10;
        float acc2 = fc2_b[a];
        for (int f4 = 0; f4 < 256 / 4; ++f4) {
            const float4 wv = *(const float4*)&fc2_W[a * 256 + f4 * 4];
            const float4 v  = *(const float4*)&s_fc1[s * 256 + f4 * 4];
            acc2 += wv.x * v.x + wv.y * v.y + wv.z * v.z + wv.w * v.w;
        }
        s_logit[s * 10 + a] = acc2;
    }
    __syncthreads();

    if (t < NSAMP) {
        float m = -1e30f;
        #pragma unroll
        for (int a = 0; a < 10; ++a) m = fmaxf(m, s_logit[t * 10 + a]);
        float sum = 0.0f;
        #pragma unroll
        for (int a = 0; a < 10; ++a) sum += __expf(s_logit[t * 10 + a] - m);
        const float lse = m + __logf(sum);
        #pragma unroll
        for (int a = 0; a < 10; ++a)
            out[(s_base + t) * 10 + a] = s_logit[t * 10 + a] - lse;
    }
}

extern "C" void kernel_launch(void* const* d_in, const int* in_sizes, int n_in,
                              void* d_out, int out_size, void* d_ws, size_t ws_size,
                              hipStream_t stream)
{
    (void)d_ws; (void)ws_size; (void)n_in; (void)out_size;

    const float* x   = (const float*)d_in[0];
    const float* Wih = (const float*)d_in[1];
    const float* Whh = (const float*)d_in[2];
    const float* bih = (const float*)d_in[3];
    const float* bhh = (const float*)d_in[4];
    const float* f1w = (const float*)d_in[5];
    const float* f1b = (const float*)d_in[6];
    const float* f2w = (const float*)d_in[7];
    const float* f2b = (const float*)d_in[8];

    const int mb = in_sizes[0] / (NOBJ * DDIM);   // 8192
    dim3 grid(mb / NSAMP), block(BLOCK);          // 512 blocks = 2 per CU
    subset_lstm_skew_kernel<<<grid, block, 0, stream>>>(
        x, Wih, Whh, bih, bhh, f1w, f1b, f2w, f2b, (float*)d_out);
}

// Round 4
// 190.778 us; speedup vs baseline: 2.0741x; 1.9338x over previous
//
#include <hip/hip_runtime.h>
#include <hip/hip_bf16.h>

#define BLOCK   512     // 8 waves; wave w owns channels w*16..w*16+15, all 4 gates
#define NSAMP   16
#define HDIM    128
#define DDIM    16
#define NOBJ    6
#define NSLOT   17

typedef __attribute__((ext_vector_type(8))) short bf16x8;
typedef __attribute__((ext_vector_type(4))) float f32x4;

constexpr int pc6(int m)  { int c = 0; for (int i = 0; i < 6; ++i) c += (m >> i) & 1; return c; }
constexpr int msb6(int m) { int b = -1; for (int i = 0; i < 6; ++i) if (m & (1 << i)) b = i; return b; }

// ---- Grouped plan: children grouped by PARENT so W_hh*h_P (zh) is computed
// ONCE per parent and shared by all children (child = 4 x-MFMAs w/ C=zh).
// Parent slot is freeable as soon as its zh+c are read (cached in regs), so
// recycling needs only 1 barrier total at NSLOT=17.
struct GChild { int jo, sl; bool bar; };
struct Plan3 {
    int    gps [32];    // parent slot per group (-1 for the root pseudo-parent)
    int    gbeg[33];    // child range per group: [gbeg[g], gbeg[g+1])
    GChild ch  [63];
    int    lvlG[8];     // group range per level d: [lvlG[d], lvlG[d+1])
    bool   ok;
};
constexpr Plan3 make_plan3() {
    Plan3 P{};
    P.ok = true;
    int  slotOf[64] = {};
    bool busy[NSLOT] = {};
    int  pendingFree[NSLOT] = {};   // parent slots read, freeable at next barrier
    int  npend = 0;
    int  g = 0, cidx = 0;
    for (int d = 1; d <= 6; ++d) {
        P.lvlG[d] = g;
        for (int Pm = 0; Pm < 64; ++Pm) {
            if (pc6(Pm) != d - 1) continue;
            if (Pm != 0 && msb6(Pm) == 5) continue;      // leaves have no children
            P.gps[g]  = (Pm == 0) ? -1 : slotOf[Pm];
            P.gbeg[g] = cidx;
            if (Pm != 0) pendingFree[npend++] = slotOf[Pm];   // zh/c read at group start
            const int j0 = (Pm == 0) ? 0 : msb6(Pm) + 1;
            for (int j = j0; j <= 5; ++j) {
                const int M = Pm | (1 << j);
                P.ch[cidx].jo  = j;
                P.ch[cidx].bar = false;
                int sl = -1;
                if (j < 5) {
                    int fs = -1;
                    for (int s = 0; s < NSLOT; ++s) if (!busy[s]) { fs = s; break; }
                    if (fs < 0) {   // recycle barrier: free all pending parents
                        P.ch[cidx].bar = true;
                        for (int i = 0; i < npend; ++i) busy[pendingFree[i]] = false;
                        npend = 0;
                        for (int s = 0; s < NSLOT; ++s) if (!busy[s]) { fs = s; break; }
                        if (fs < 0) P.ok = false;
                    }
                    if (fs >= 0) { busy[fs] = true; slotOf[M] = fs; sl = fs; }
                }
                P.ch[cidx].sl = sl;
                ++cidx;
            }
            ++g;
        }
        // level-end barrier frees all parents read during this level
        for (int i = 0; i < npend; ++i) busy[pendingFree[i]] = false;
        npend = 0;
    }
    P.lvlG[7] = g;
    P.gbeg[g] = cidx;
    if (g != 32 || cidx != 63) P.ok = false;
    return P;
}
constexpr Plan3 PL3 = make_plan3();
static_assert(PL3.ok, "plan allocation failed");
static_assert(PL3.lvlG[7] == 32, "32 groups expected");
static_assert(PL3.gbeg[32] == 63, "63 children expected");

#define LOG2E   1.44269504f
#define TWOL2E  2.88539008f
#define SLOT_SH 2048            // shorts per slot (4 KB), h and c pools

__device__ __forceinline__ unsigned short f2bf(float x) {
    union { float f; unsigned int u; } a; a.f = x;
    unsigned int r = (a.u + 0x7FFFu + ((a.u >> 16) & 1u)) >> 16;
    return (unsigned short)r;
}
__device__ __forceinline__ unsigned pk2(float a, float b) {
    union { __hip_bfloat162 h; unsigned u; } z;
    z.h = __float22bfloat162_rn(float2{a, b});
    return z.u;
}
__device__ __forceinline__ float bflo(unsigned p) {
    union { unsigned u; float f; } a; a.u = p << 16; return a.f;
}
__device__ __forceinline__ float bfhi(unsigned p) {
    union { unsigned u; float f; } a; a.u = p & 0xFFFF0000u; return a.f;
}

// h pool: hs[((slot*16 + kslot)*NSAMP + n)*8 + j] = h[ch = kslot*8+j][sample n]
//   B-frag chunk q, lane (quad,m16): kslot = q*4+quad -> 16B-aligned ds_read_b128
//   wave w writes ch = w*16+quad*4+r at kslot = w*2+(quad>>1), j = (quad&1)*4+r
// c pool: csb[((slot*32 + w*4+quad)*NSAMP + n)*4 + r], bf16 (b64/lane)
// Register model (R0-R3 evidence): with MFMA present the unified RF splits
//   ~half arch / half acc. waves_per_eu(2,4) -> 256 total -> arch cap 128.
//   wf(80)+misc stay arch; zh/acc accumulators land in the AGPR half.

__global__ __launch_bounds__(BLOCK)
__attribute__((amdgpu_waves_per_eu(2, 4)))   // R0-verified envelope: no spill
void subset_lstm_skew_kernel(
    const float* __restrict__ x_input,
    const float* __restrict__ W_ih,
    const float* __restrict__ W_hh,
    const float* __restrict__ b_ih,
    const float* __restrict__ b_hh,
    const float* __restrict__ fc1_W,
    const float* __restrict__ fc1_b,
    const float* __restrict__ fc2_W,
    const float* __restrict__ fc2_b,
    float* __restrict__ out)
{
    __shared__ __align__(16) unsigned short hs [NSLOT * SLOT_SH];       // 68 KB
    __shared__ __align__(16) unsigned short csb[NSLOT * SLOT_SH];       // 68 KB
    __shared__ __align__(16) unsigned short xb[NOBJ * 4 * NSAMP * 8];   // 6 KB
    float* s_maxh  = (float*)hs;                 // 8 KB  (post-LSTM alias)
    float* s_fc1   = (float*)(hs + 4096);        // 16 KB (post-LSTM alias)
    float* s_logit = (float*)xb;

    const int t      = threadIdx.x;
    const int w      = t >> 6;
    const int lane   = t & 63;
    const int quad   = lane >> 4;
    const int m16    = lane & 15;
    const int s_base = blockIdx.x * NSAMP;

    // ---- x B-chunks: xb[obj][quad'][n][j]; quad2 j0 = 1.0 (bias lane), quad3 zero ----
    for (int idx = t; idx < NOBJ * 4 * NSAMP * 8; idx += BLOCK) {
        const int j = idx & 7, n = (idx >> 3) & 15, q = (idx >> 7) & 3, obj = idx >> 9;
        float v;
        if (q < 2) v = x_input[(s_base + n) * (NOBJ * DDIM) + obj * DDIM + q * 8 + j];
        else       v = (q == 2 && j == 0) ? 1.0f : 0.0f;
        xb[idx] = f2bf(v);
    }

    // ---- persistent A-frags wf[gate][chunk], PRE-SCALED (verified R8-R13) ----
    bf16x8 wf[4][5];
    #pragma unroll
    for (int g = 0; g < 4; ++g) {
        const float sc = (g == 2) ? TWOL2E : -LOG2E;
        const int grow = g * HDIM + w * 16 + m16;
        const float* whr = W_hh + grow * HDIM;
        const float* wir = W_ih + grow * DDIM;
        #pragma unroll
        for (int q = 0; q < 4; ++q) {
            union { unsigned short u[8]; bf16x8 v; } pk;
            #pragma unroll
            for (int j = 0; j < 8; ++j)
                pk.u[j] = f2bf(sc * whr[q * 32 + quad * 8 + j]);
            wf[g][q] = pk.v;
        }
        {
            union { unsigned short u[8]; bf16x8 v; } pk;
            #pragma unroll
            for (int j = 0; j < 8; ++j) {
                float v = 0.0f;
                if (quad < 2) v = sc * wir[quad * 8 + j];
                else if (quad == 2 && j == 0) v = sc * (b_ih[grow] + b_hh[grow]);
                pk.u[j] = f2bf(v);
            }
            wf[g][4] = pk.v;
        }
    }

    float mh[4] = {-1e30f, -1e30f, -1e30f, -1e30f};
    const int kslot = w * 2 + (quad >> 1);
    unsigned short* const c_lane = &csb[(((w * 4 + quad) * NSAMP) + m16) * 4];

    // fused pointwise (verified R9-R13); cprev passed in (shared per group)
    auto pointwise_node = [&](const f32x4 (&acc)[4], uint2 cpk, int sl) {
        float cn4[4], hn4[4];
        #pragma unroll
        for (int r = 0; r < 4; ++r) {
            const unsigned p = (r < 2) ? cpk.x : cpk.y;
            const float cprev = (r & 1) ? bfhi(p) : bflo(p);
            const float u  = 1.0f + __builtin_amdgcn_exp2f(acc[0][r]);
            const float q  = 1.0f + __builtin_amdgcn_exp2f(acc[1][r]);
            const float v  = 1.0f + __builtin_amdgcn_exp2f(acc[2][r]);
            const float qo = 1.0f + __builtin_amdgcn_exp2f(acc[3][r]);
            const float uv  = u * v;
            const float num = fmaf(q, v - 2.0f, cprev * uv);
            const float cn  = num * __builtin_amdgcn_rcpf(q * uv);
            const float wt  = 1.0f + __builtin_amdgcn_exp2f(TWOL2E * cn);
            const float h   = (wt - 2.0f) * __builtin_amdgcn_rcpf(qo * wt);
            cn4[r] = cn; hn4[r] = h;
            mh[r] = fmaxf(mh[r], h);
        }
        if (sl >= 0) {
            uint2 cw; cw.x = pk2(cn4[0], cn4[1]); cw.y = pk2(cn4[2], cn4[3]);
            *(uint2*)(c_lane + sl * SLOT_SH) = cw;
            uint2 hw; hw.x = pk2(hn4[0], hn4[1]); hw.y = pk2(hn4[2], hn4[3]);
            *(uint2*)&hs[((sl * 16 + kslot) * NSAMP + m16) * 8 + (quad & 1) * 4] = hw;
        }
    };

    // ---- main loop: per level, per parent-group ----
    #pragma unroll
    for (int d = 1; d <= 6; ++d) {
        __syncthreads();
        const int gBeg = PL3.lvlG[d];
        const int gEnd = PL3.lvlG[d + 1];
        #pragma unroll
        for (int gi = gBeg; gi < gEnd; ++gi) {
            const int ps = PL3.gps[gi];
            f32x4 zh[4];
            uint2 cpkP; cpkP.x = 0u; cpkP.y = 0u;
            #pragma unroll
            for (int g2 = 0; g2 < 4; ++g2) zh[g2] = f32x4{0.f, 0.f, 0.f, 0.f};
            if (ps >= 0) {
                cpkP = *(const uint2*)(c_lane + ps * SLOT_SH);
                #pragma unroll
                for (int q = 0; q < 4; ++q) {
                    const bf16x8 bh = *(const bf16x8*)
                        &hs[((ps * 16 + q * 4 + quad) * NSAMP + m16) * 8];
                    #pragma unroll
                    for (int g2 = 0; g2 < 4; ++g2)
                        zh[g2] = __builtin_amdgcn_mfma_f32_16x16x32_bf16(
                            wf[g2][q], bh, zh[g2], 0, 0, 0);
                }
            }
            #pragma unroll
            for (int ci = PL3.gbeg[gi]; ci < PL3.gbeg[gi + 1]; ++ci) {
                if (PL3.ch[ci].bar) __syncthreads();   // recycle barrier (constexpr)
                const bf16x8 bfx = *(const bf16x8*)
                    &xb[((PL3.ch[ci].jo * 4 + quad) * NSAMP + m16) * 8];
                f32x4 acc[4];
                #pragma unroll
                for (int g2 = 0; g2 < 4; ++g2)
                    acc[g2] = __builtin_amdgcn_mfma_f32_16x16x32_bf16(
                        wf[g2][4], bfx, zh[g2], 0, 0, 0);
                pointwise_node(acc, cpkP, PL3.ch[ci].sl);
            }
        }
    }

    __syncthreads();   // pools dead; reuse hs for epilogue
    {
        float4 v; v.x = mh[0]; v.y = mh[1]; v.z = mh[2]; v.w = mh[3];
        *(float4*)&s_maxh[m16 * HDIM + w * 16 + quad * 4] = v;
    }
    __syncthreads();

    // ---- FC1: f = t&255, sample half t>>8 (8 samples each) ----
    {
        const int f  = t & 255;
        const int sh = t >> 8;
        float a1[8];
        #pragma unroll
        for (int s = 0; s < 8; ++s) a1[s] = fc1_b[f];
        for (int k4 = 0; k4 < HDIM / 4; ++k4) {
            const float4 wv = *(const float4*)&fc1_W[f * HDIM + k4 * 4];
            #pragma unroll
            for (int s = 0; s < 8; ++s) {
                const float4 h4 = *(const float4*)&s_maxh[(sh * 8 + s) * HDIM + k4 * 4];
                a1[s] += wv.x * h4.x + wv.y * h4.y + wv.z * h4.z + wv.w * h4.w;
            }
        }
        #pragma unroll
        for (int s = 0; s < 8; ++s)
            s_fc1[(sh * 8 + s) * 256 + f] = fmaxf(a1[s], 0.0f);
    }
    __syncthreads();

    if (t < NSAMP * 10) {
        const int s = t / 10, a = t % 10;
        float acc2 = fc2_b[a];
        for (int f4 = 0; f4 < 256 / 4; ++f4) {
            const float4 wv = *(const float4*)&fc2_W[a * 256 + f4 * 4];
            const float4 v  = *(const float4*)&s_fc1[s * 256 + f4 * 4];
            acc2 += wv.x * v.x + wv.y * v.y + wv.z * v.z + wv.w * v.w;
        }
        s_logit[s * 10 + a] = acc2;
    }
    __syncthreads();

    if (t < NSAMP) {
        float m = -1e30f;
        #pragma unroll
        for (int a = 0; a < 10; ++a) m = fmaxf(m, s_logit[t * 10 + a]);
        float sum = 0.0f;
        #pragma unroll
        for (int a = 0; a < 10; ++a) sum += __expf(s_logit[t * 10 + a] - m);
        const float lse = m + __logf(sum);
        #pragma unroll
        for (int a = 0; a < 10; ++a)
            out[(s_base + t) * 10 + a] = s_logit[t * 10 + a] - lse;
    }
}

extern "C" void kernel_launch(void* const* d_in, const int* in_sizes, int n_in,
                              void* d_out, int out_size, void* d_ws, size_t ws_size,
                              hipStream_t stream)
{
    (void)d_ws; (void)ws_size; (void)n_in; (void)out_size;

    const float* x   = (const float*)d_in[0];
    const float* Wih = (const float*)d_in[1];
    const float* Whh = (const float*)d_in[2];
    const float* bih = (const float*)d_in[3];
    const float* bhh = (const float*)d_in[4];
    const float* f1w = (const float*)d_in[5];
    const float* f1b = (const float*)d_in[6];
    const float* f2w = (const float*)d_in[7];
    const float* f2b = (const float*)d_in[8];

    const int mb = in_sizes[0] / (NOBJ * DDIM);   // 8192
    dim3 grid(mb / NSAMP), block(BLOCK);
    subset_lstm_skew_kernel<<<grid, block, 0, stream>>>(
        x, Wih, Whh, bih, bhh, f1w, f1b, f2w, f2b, (float*)d_out);
}

// Round 5
// 190.662 us; speedup vs baseline: 2.0754x; 1.0006x over previous
//
#include <hip/hip_runtime.h>
#include <hip/hip_bf16.h>

#define BLOCK   512     // 8 waves; wave w owns channels w*16..w*16+15, all 4 gates
#define NSAMP   16
#define HDIM    128
#define DDIM    16
#define NOBJ    6
#define NSLOT   17

typedef __attribute__((ext_vector_type(8))) short bf16x8;
typedef __attribute__((ext_vector_type(4))) float f32x4;

constexpr int pc6(int m)  { int c = 0; for (int i = 0; i < 6; ++i) c += (m >> i) & 1; return c; }
constexpr int msb6(int m) { int b = -1; for (int i = 0; i < 6; ++i) if (m & (1 << i)) b = i; return b; }

// ---- Grouped plan: children grouped by PARENT so W_hh*h_P (zh) is computed
// ONCE per parent and shared by all children (child = 4 x-MFMAs w/ C=zh).
// Parent slot is freeable as soon as its zh+c are read (cached in regs), so
// recycling needs only 1 barrier total at NSLOT=17.  (verified R4)
struct GChild { int jo, sl; bool bar; };
struct Plan3 {
    int    gps [32];    // parent slot per group (-1 for the root pseudo-parent)
    int    gbeg[33];    // child range per group: [gbeg[g], gbeg[g+1])
    GChild ch  [63];
    int    lvlG[8];     // group range per level d: [lvlG[d], lvlG[d+1])
    bool   ok;
};
constexpr Plan3 make_plan3() {
    Plan3 P{};
    P.ok = true;
    int  slotOf[64] = {};
    bool busy[NSLOT] = {};
    int  pendingFree[NSLOT] = {};   // parent slots read, freeable at next barrier
    int  npend = 0;
    int  g = 0, cidx = 0;
    for (int d = 1; d <= 6; ++d) {
        P.lvlG[d] = g;
        for (int Pm = 0; Pm < 64; ++Pm) {
            if (pc6(Pm) != d - 1) continue;
            if (Pm != 0 && msb6(Pm) == 5) continue;      // leaves have no children
            P.gps[g]  = (Pm == 0) ? -1 : slotOf[Pm];
            P.gbeg[g] = cidx;
            if (Pm != 0) pendingFree[npend++] = slotOf[Pm];   // zh/c read at group start
            const int j0 = (Pm == 0) ? 0 : msb6(Pm) + 1;
            for (int j = j0; j <= 5; ++j) {
                const int M = Pm | (1 << j);
                P.ch[cidx].jo  = j;
                P.ch[cidx].bar = false;
                int sl = -1;
                if (j < 5) {
                    int fs = -1;
                    for (int s = 0; s < NSLOT; ++s) if (!busy[s]) { fs = s; break; }
                    if (fs < 0) {   // recycle barrier: free all pending parents
                        P.ch[cidx].bar = true;
                        for (int i = 0; i < npend; ++i) busy[pendingFree[i]] = false;
                        npend = 0;
                        for (int s = 0; s < NSLOT; ++s) if (!busy[s]) { fs = s; break; }
                        if (fs < 0) P.ok = false;
                    }
                    if (fs >= 0) { busy[fs] = true; slotOf[M] = fs; sl = fs; }
                }
                P.ch[cidx].sl = sl;
                ++cidx;
            }
            ++g;
        }
        // level-end barrier frees all parents read during this level
        for (int i = 0; i < npend; ++i) busy[pendingFree[i]] = false;
        npend = 0;
    }
    P.lvlG[7] = g;
    P.gbeg[g] = cidx;
    if (g != 32 || cidx != 63) P.ok = false;
    return P;
}
constexpr Plan3 PL3 = make_plan3();
static_assert(PL3.ok, "plan allocation failed");
static_assert(PL3.lvlG[7] == 32, "32 groups expected");
static_assert(PL3.gbeg[32] == 63, "63 children expected");

#define LOG2E   1.44269504f
#define TWOL2E  2.88539008f
#define SLOT_SH 2048            // shorts per slot (4 KB), h and c pools

__device__ __forceinline__ unsigned short f2bf(float x) {
    union { float f; unsigned int u; } a; a.f = x;
    unsigned int r = (a.u + 0x7FFFu + ((a.u >> 16) & 1u)) >> 16;
    return (unsigned short)r;
}
__device__ __forceinline__ unsigned pk2(float a, float b) {
    union { __hip_bfloat162 h; unsigned u; } z;
    z.h = __float22bfloat162_rn(float2{a, b});
    return z.u;
}
__device__ __forceinline__ float bflo(unsigned p) {
    union { unsigned u; float f; } a; a.u = p << 16; return a.f;
}
__device__ __forceinline__ float bfhi(unsigned p) {
    union { unsigned u; float f; } a; a.u = p & 0xFFFF0000u; return a.f;
}

// h pool: hs[((slot*16 + kslot)*NSAMP + n)*8 + j] = h[ch = kslot*8+j][sample n]
//   B-frag chunk q, lane (quad,m16): kslot = q*4+quad -> 16B-aligned ds_read_b128
//   wave w writes ch = w*16+quad*4+r at kslot = w*2+(quad>>1), j = (quad&1)*4+r
// c pool: csb[((slot*32 + w*4+quad)*NSAMP + n)*4 + r], bf16 (b64/lane)
// Register model (R0-R4 evidence): with MFMA present the unified RF splits
//   ~half arch / half acc; waves_per_eu(2,4) -> arch cap 128. wf(80)+misc
//   stay arch (R4: VGPR_Count=104); zh/acc accumulators go to the AGPR half.
// R5: software pipeline — (a) previous group's last-child pointwise executes
//   during the next group's zh MFMA chain; (b) within-group child acc
//   ping-pong (R0-verified). All plan indices constexpr after full unroll.

__global__ __launch_bounds__(BLOCK)
__attribute__((amdgpu_waves_per_eu(2, 4)))   // R0/R4-verified envelope: no spill
void subset_lstm_skew_kernel(
    const float* __restrict__ x_input,
    const float* __restrict__ W_ih,
    const float* __restrict__ W_hh,
    const float* __restrict__ b_ih,
    const float* __restrict__ b_hh,
    const float* __restrict__ fc1_W,
    const float* __restrict__ fc1_b,
    const float* __restrict__ fc2_W,
    const float* __restrict__ fc2_b,
    float* __restrict__ out)
{
    __shared__ __align__(16) unsigned short hs [NSLOT * SLOT_SH];       // 68 KB
    __shared__ __align__(16) unsigned short csb[NSLOT * SLOT_SH];       // 68 KB
    __shared__ __align__(16) unsigned short xb[NOBJ * 4 * NSAMP * 8];   // 6 KB
    float* s_maxh  = (float*)hs;                 // 8 KB  (post-LSTM alias)
    float* s_fc1   = (float*)(hs + 4096);        // 16 KB (post-LSTM alias)
    float* s_logit = (float*)xb;

    const int t      = threadIdx.x;
    const int w      = t >> 6;
    const int lane   = t & 63;
    const int quad   = lane >> 4;
    const int m16    = lane & 15;
    const int s_base = blockIdx.x * NSAMP;

    // ---- x B-chunks: xb[obj][quad'][n][j]; quad2 j0 = 1.0 (bias lane), quad3 zero ----
    for (int idx = t; idx < NOBJ * 4 * NSAMP * 8; idx += BLOCK) {
        const int j = idx & 7, n = (idx >> 3) & 15, q = (idx >> 7) & 3, obj = idx >> 9;
        float v;
        if (q < 2) v = x_input[(s_base + n) * (NOBJ * DDIM) + obj * DDIM + q * 8 + j];
        else       v = (q == 2 && j == 0) ? 1.0f : 0.0f;
        xb[idx] = f2bf(v);
    }

    // ---- persistent A-frags wf[gate][chunk], PRE-SCALED (verified R8-R13) ----
    bf16x8 wf[4][5];
    #pragma unroll
    for (int g = 0; g < 4; ++g) {
        const float sc = (g == 2) ? TWOL2E : -LOG2E;
        const int grow = g * HDIM + w * 16 + m16;
        const float* whr = W_hh + grow * HDIM;
        const float* wir = W_ih + grow * DDIM;
        #pragma unroll
        for (int q = 0; q < 4; ++q) {
            union { unsigned short u[8]; bf16x8 v; } pk;
            #pragma unroll
            for (int j = 0; j < 8; ++j)
                pk.u[j] = f2bf(sc * whr[q * 32 + quad * 8 + j]);
            wf[g][q] = pk.v;
        }
        {
            union { unsigned short u[8]; bf16x8 v; } pk;
            #pragma unroll
            for (int j = 0; j < 8; ++j) {
                float v = 0.0f;
                if (quad < 2) v = sc * wir[quad * 8 + j];
                else if (quad == 2 && j == 0) v = sc * (b_ih[grow] + b_hh[grow]);
                pk.u[j] = f2bf(v);
            }
            wf[g][4] = pk.v;
        }
    }

    float mh[4] = {-1e30f, -1e30f, -1e30f, -1e30f};
    const int kslot = w * 2 + (quad >> 1);
    unsigned short* const c_lane = &csb[(((w * 4 + quad) * NSAMP) + m16) * 4];

    // fused pointwise (verified R9-R13); cprev passed in (shared per group)
    auto pointwise_node = [&](const f32x4 (&acc)[4], uint2 cpk, int sl) {
        float cn4[4], hn4[4];
        #pragma unroll
        for (int r = 0; r < 4; ++r) {
            const unsigned p = (r < 2) ? cpk.x : cpk.y;
            const float cprev = (r & 1) ? bfhi(p) : bflo(p);
            const float u  = 1.0f + __builtin_amdgcn_exp2f(acc[0][r]);
            const float q  = 1.0f + __builtin_amdgcn_exp2f(acc[1][r]);
            const float v  = 1.0f + __builtin_amdgcn_exp2f(acc[2][r]);
            const float qo = 1.0f + __builtin_amdgcn_exp2f(acc[3][r]);
            const float uv  = u * v;
            const float num = fmaf(q, v - 2.0f, cprev * uv);
            const float cn  = num * __builtin_amdgcn_rcpf(q * uv);
            const float wt  = 1.0f + __builtin_amdgcn_exp2f(TWOL2E * cn);
            const float h   = (wt - 2.0f) * __builtin_amdgcn_rcpf(qo * wt);
            cn4[r] = cn; hn4[r] = h;
            mh[r] = fmaxf(mh[r], h);
        }
        if (sl >= 0) {
            uint2 cw; cw.x = pk2(cn4[0], cn4[1]); cw.y = pk2(cn4[2], cn4[3]);
            *(uint2*)(c_lane + sl * SLOT_SH) = cw;
            uint2 hw; hw.x = pk2(hn4[0], hn4[1]); hw.y = pk2(hn4[2], hn4[3]);
            *(uint2*)&hs[((sl * 16 + kslot) * NSAMP + m16) * 8 + (quad & 1) * 4] = hw;
        }
    };

    // ---- main loop: per level, per parent-group, software-pipelined ----
    #pragma unroll
    for (int d = 1; d <= 6; ++d) {
        __syncthreads();
        const int gBeg  = PL3.lvlG[d];
        const int gEnd  = PL3.lvlG[d + 1];
        const int cLvl0 = PL3.gbeg[gBeg];
        f32x4 accP[2][4];       // child acc ping-pong, parity = (ci - cLvl0) & 1
        uint2 cpP[2];           // parent-c snapshot for each pending child
        #pragma unroll
        for (int gi = gBeg; gi < gEnd; ++gi) {
            const int ps = PL3.gps[gi];
            const int cB = PL3.gbeg[gi];
            const int cE = PL3.gbeg[gi + 1];
            // -- zh chain for this group (MFMA pipe starts first) --
            f32x4 zh[4];
            uint2 cpkCur; cpkCur.x = 0u; cpkCur.y = 0u;
            #pragma unroll
            for (int g2 = 0; g2 < 4; ++g2) zh[g2] = f32x4{0.f, 0.f, 0.f, 0.f};
            if (ps >= 0) {
                cpkCur = *(const uint2*)(c_lane + ps * SLOT_SH);
                #pragma unroll
                for (int q = 0; q < 4; ++q) {
                    const bf16x8 bh = *(const bf16x8*)
                        &hs[((ps * 16 + q * 4 + quad) * NSAMP + m16) * 8];
                    #pragma unroll
                    for (int g2 = 0; g2 < 4; ++g2)
                        zh[g2] = __builtin_amdgcn_mfma_f32_16x16x32_bf16(
                            wf[g2][q], bh, zh[g2], 0, 0, 0);
                }
            }
            // -- pointwise of previous group's last child: VALU overlaps zh chain --
            if (gi > gBeg) {
                const int pc   = cB - 1;
                const int ppar = (pc - cLvl0) & 1;
                pointwise_node(accP[ppar], cpP[ppar], PL3.ch[pc].sl);
            }
            // -- children: x-MFMA into ping-pong acc, deferred pointwise --
            #pragma unroll
            for (int ci = cB; ci < cE; ++ci) {
                const int par = (ci - cLvl0) & 1;
                if (PL3.ch[ci].bar) __syncthreads();   // recycle barrier (constexpr)
                const bf16x8 bfx = *(const bf16x8*)
                    &xb[((PL3.ch[ci].jo * 4 + quad) * NSAMP + m16) * 8];
                #pragma unroll
                for (int g2 = 0; g2 < 4; ++g2)
                    accP[par][g2] = __builtin_amdgcn_mfma_f32_16x16x32_bf16(
                        wf[g2][4], bfx, zh[g2], 0, 0, 0);
                cpP[par] = cpkCur;
                if (ci > cB) {
                    const int par1 = par ^ 1;
                    pointwise_node(accP[par1], cpP[par1], PL3.ch[ci - 1].sl);
                }
            }
        }
        // -- flush the level's last pending child before the next level barrier --
        {
            const int pc   = PL3.gbeg[gEnd] - 1;
            const int ppar = (pc - cLvl0) & 1;
            pointwise_node(accP[ppar], cpP[ppar], PL3.ch[pc].sl);
        }
    }

    __syncthreads();   // pools dead; reuse hs for epilogue
    {
        float4 v; v.x = mh[0]; v.y = mh[1]; v.z = mh[2]; v.w = mh[3];
        *(float4*)&s_maxh[m16 * HDIM + w * 16 + quad * 4] = v;
    }
    __syncthreads();

    // ---- FC1: f = t&255, sample half t>>8 (8 samples each) ----
    {
        const int f  = t & 255;
        const int sh = t >> 8;
        float a1[8];
        #pragma unroll
        for (int s = 0; s < 8; ++s) a1[s] = fc1_b[f];
        for (int k4 = 0; k4 < HDIM / 4; ++k4) {
            const float4 wv = *(const float4*)&fc1_W[f * HDIM + k4 * 4];
            #pragma unroll
            for (int s = 0; s < 8; ++s) {
                const float4 h4 = *(const float4*)&s_maxh[(sh * 8 + s) * HDIM + k4 * 4];
                a1[s] += wv.x * h4.x + wv.y * h4.y + wv.z * h4.z + wv.w * h4.w;
            }
        }
        #pragma unroll
        for (int s = 0; s < 8; ++s)
            s_fc1[(sh * 8 + s) * 256 + f] = fmaxf(a1[s], 0.0f);
    }
    __syncthreads();

    if (t < NSAMP * 10) {
        const int s = t / 10, a = t % 10;
        float acc2 = fc2_b[a];
        for (int f4 = 0; f4 < 256 / 4; ++f4) {
            const float4 wv = *(const float4*)&fc2_W[a * 256 + f4 * 4];
            const float4 v  = *(const float4*)&s_fc1[s * 256 + f4 * 4];
            acc2 += wv.x * v.x + wv.y * v.y + wv.z * v.z + wv.w * v.w;
        }
        s_logit[s * 10 + a] = acc2;
    }
    __syncthreads();

    if (t < NSAMP) {
        float m = -1e30f;
        #pragma unroll
        for (int a = 0; a < 10; ++a) m = fmaxf(m, s_logit[t * 10 + a]);
        float sum = 0.0f;
        #pragma unroll
        for (int a = 0; a < 10; ++a) sum += __expf(s_logit[t * 10 + a] - m);
        const float lse = m + __logf(sum);
        #pragma unroll
        for (int a = 0; a < 10; ++a)
            out[(s_base + t) * 10 + a] = s_logit[t * 10 + a] - lse;
    }
}

extern "C" void kernel_launch(void* const* d_in, const int* in_sizes, int n_in,
                              void* d_out, int out_size, void* d_ws, size_t ws_size,
                              hipStream_t stream)
{
    (void)d_ws; (void)ws_size; (void)n_in; (void)out_size;

    const float* x   = (const float*)d_in[0];
    const float* Wih = (const float*)d_in[1];
    const float* Whh = (const float*)d_in[2];
    const float* bih = (const float*)d_in[3];
    const float* bhh = (const float*)d_in[4];
    const float* f1w = (const float*)d_in[5];
    const float* f1b = (const float*)d_in[6];
    const float* f2w = (const float*)d_in[7];
    const float* f2b = (const float*)d_in[8];

    const int mb = in_sizes[0] / (NOBJ * DDIM);   // 8192
    dim3 grid(mb / NSAMP), block(BLOCK);
    subset_lstm_skew_kernel<<<grid, block, 0, stream>>>(
        x, Wih, Whh, bih, bhh, f1w, f1b, f2w, f2b, (float*)d_out);
}

// Round 6
// 190.443 us; speedup vs baseline: 2.0778x; 1.0012x over previous
//
#include <hip/hip_runtime.h>
#include <hip/hip_bf16.h>

#define BLOCK   512     // 8 waves; wave w owns channels w*16..w*16+15, all 4 gates
#define NSAMP   16
#define HDIM    128
#define DDIM    16
#define NOBJ    6
#define NSLOT   14

typedef __attribute__((ext_vector_type(8))) short bf16x8;
typedef __attribute__((ext_vector_type(4))) float f32x4;

constexpr int pc6(int m)  { int c = 0; for (int i = 0; i < 6; ++i) c += (m >> i) & 1; return c; }
constexpr int msb6(int m) { int b = -1; for (int i = 0; i < 6; ++i) if (m & (1 << i)) b = i; return b; }

// ---- Grouped plan (verified R4): children grouped by PARENT so W_hh*h_P (zh)
// is computed ONCE per parent. Parent slot freeable once zh/c read (cached in
// regs); allocator inserts recycle barriers when the 14-slot pool is full.
struct GChild { int jo, sl; bool bar; };
struct Plan3 {
    int    gps [32];    // parent slot per group (-1 for the root pseudo-parent)
    int    gbeg[33];    // child range per group: [gbeg[g], gbeg[g+1])
    GChild ch  [63];
    int    lvlG[8];     // group range per level d: [lvlG[d], lvlG[d+1])
    bool   ok;
};
constexpr Plan3 make_plan3() {
    Plan3 P{};
    P.ok = true;
    int  slotOf[64] = {};
    bool busy[NSLOT] = {};
    int  pendingFree[NSLOT] = {};   // parent slots read, freeable at next barrier
    int  npend = 0;
    int  g = 0, cidx = 0;
    for (int d = 1; d <= 6; ++d) {
        P.lvlG[d] = g;
        for (int Pm = 0; Pm < 64; ++Pm) {
            if (pc6(Pm) != d - 1) continue;
            if (Pm != 0 && msb6(Pm) == 5) continue;      // leaves have no children
            P.gps[g]  = (Pm == 0) ? -1 : slotOf[Pm];
            P.gbeg[g] = cidx;
            if (Pm != 0) pendingFree[npend++] = slotOf[Pm];   // zh/c read at group start
            const int j0 = (Pm == 0) ? 0 : msb6(Pm) + 1;
            for (int j = j0; j <= 5; ++j) {
                const int M = Pm | (1 << j);
                P.ch[cidx].jo  = j;
                P.ch[cidx].bar = false;
                int sl = -1;
                if (j < 5) {
                    int fs = -1;
                    for (int s = 0; s < NSLOT; ++s) if (!busy[s]) { fs = s; break; }
                    if (fs < 0) {   // recycle barrier: free all pending parents
                        P.ch[cidx].bar = true;
                        if (npend == 0) P.ok = false;
                        for (int i = 0; i < npend; ++i) busy[pendingFree[i]] = false;
                        npend = 0;
                        for (int s = 0; s < NSLOT; ++s) if (!busy[s]) { fs = s; break; }
                        if (fs < 0) P.ok = false;
                    }
                    if (fs >= 0) { busy[fs] = true; slotOf[M] = fs; sl = fs; }
                }
                P.ch[cidx].sl = sl;
                ++cidx;
            }
            ++g;
        }
        // level-end barrier frees all parents read during this level
        for (int i = 0; i < npend; ++i) busy[pendingFree[i]] = false;
        npend = 0;
    }
    P.lvlG[7] = g;
    P.gbeg[g] = cidx;
    if (g != 32 || cidx != 63) P.ok = false;
    return P;
}
constexpr Plan3 PL3 = make_plan3();
static_assert(PL3.ok, "plan allocation failed");
static_assert(PL3.lvlG[7] == 32, "32 groups expected");
static_assert(PL3.gbeg[32] == 63, "63 children expected");

#define LOG2E   1.44269504f
#define TWOL2E  2.88539008f
#define SLOT_SH 2048            // shorts per slot (4 KB), h pool

__device__ __forceinline__ unsigned short f2bf(float x) {
    union { float f; unsigned int u; } a; a.f = x;
    unsigned int r = (a.u + 0x7FFFu + ((a.u >> 16) & 1u)) >> 16;
    return (unsigned short)r;
}
__device__ __forceinline__ unsigned pk2(float a, float b) {
    union { __hip_bfloat162 h; unsigned u; } z;
    z.h = __float22bfloat162_rn(float2{a, b});
    return z.u;
}

// h pool: hs[((slot*16 + kslot)*NSAMP + n)*8 + j] = h[ch = kslot*8+j][sample n]
//   B-frag chunk q, lane (quad,m16): kslot = q*4+quad -> 16B-aligned ds_read_b128
//   wave w writes ch = w*16+quad*4+r at kslot = w*2+(quad>>1), j = (quad&1)*4+r
// c state: f32 in registers c_slots[NSLOT][4], statically indexed (no LDS pool,
//   no bf16 rounding).  Overflow spills to AGPRs at the (2,4) envelope (R0-R5
//   model: arch cap 128, acc half free) — FETCH_SIZE is the scratch tripwire.
// Ex pool (NEW): Ex[j3][gate][w][quad*16+m16][r] = exp2(zx) in f32 for objects
//   3..5 (56 of 63 children).  exp2(zh+zx) = Eh*Ex turns those children's 4
//   exp2 + 4 MFMA into 4 FMA + 1 ds_read_b128 per gate-set.  f32 -> exact.

__global__ __launch_bounds__(BLOCK)
__attribute__((amdgpu_waves_per_eu(2, 4)))   // R0/R4-verified envelope: no spill
void subset_lstm_skew_kernel(
    const float* __restrict__ x_input,
    const float* __restrict__ W_ih,
    const float* __restrict__ W_hh,
    const float* __restrict__ b_ih,
    const float* __restrict__ b_hh,
    const float* __restrict__ fc1_W,
    const float* __restrict__ fc1_b,
    const float* __restrict__ fc2_W,
    const float* __restrict__ fc2_b,
    float* __restrict__ out)
{
    __shared__ __align__(16) unsigned short hs [NSLOT * SLOT_SH];       // 56 KB
    __shared__ __align__(16) float          Exs[3 * 4 * 8 * 64 * 4];    // 96 KB
    __shared__ __align__(16) unsigned short xb[NOBJ * 4 * NSAMP * 8];   // 6 KB
    float* s_maxh  = (float*)hs;                 // 8 KB  (post-LSTM alias)
    float* s_fc1   = (float*)(hs + 4096);        // 16 KB (post-LSTM alias)
    float* s_logit = (float*)xb;

    const int t      = threadIdx.x;
    const int w      = t >> 6;
    const int lane   = t & 63;
    const int quad   = lane >> 4;
    const int m16    = lane & 15;
    const int s_base = blockIdx.x * NSAMP;

    // ---- x B-chunks: xb[obj][quad'][n][j]; quad2 j0 = 1.0 (bias lane), quad3 zero ----
    for (int idx = t; idx < NOBJ * 4 * NSAMP * 8; idx += BLOCK) {
        const int j = idx & 7, n = (idx >> 3) & 15, q = (idx >> 7) & 3, obj = idx >> 9;
        float v;
        if (q < 2) v = x_input[(s_base + n) * (NOBJ * DDIM) + obj * DDIM + q * 8 + j];
        else       v = (q == 2 && j == 0) ? 1.0f : 0.0f;
        xb[idx] = f2bf(v);
    }

    // ---- persistent A-frags wf[gate][chunk], PRE-SCALED (verified R8-R13) ----
    bf16x8 wf[4][5];
    #pragma unroll
    for (int g = 0; g < 4; ++g) {
        const float sc = (g == 2) ? TWOL2E : -LOG2E;
        const int grow = g * HDIM + w * 16 + m16;
        const float* whr = W_hh + grow * HDIM;
        const float* wir = W_ih + grow * DDIM;
        #pragma unroll
        for (int q = 0; q < 4; ++q) {
            union { unsigned short u[8]; bf16x8 v; } pk;
            #pragma unroll
            for (int j = 0; j < 8; ++j)
                pk.u[j] = f2bf(sc * whr[q * 32 + quad * 8 + j]);
            wf[g][q] = pk.v;
        }
        {
            union { unsigned short u[8]; bf16x8 v; } pk;
            #pragma unroll
            for (int j = 0; j < 8; ++j) {
                float v = 0.0f;
                if (quad < 2) v = sc * wir[quad * 8 + j];
                else if (quad == 2 && j == 0) v = sc * (b_ih[grow] + b_hh[grow]);
                pk.u[j] = f2bf(v);
            }
            wf[g][4] = pk.v;
        }
    }

    __syncthreads();    // xb ready (needed for Ex build)

    // ---- Ex build: objects 3..5, zx via x-MFMA (C=0), exp2 -> f32 LDS ----
    // Wave w writes/reads ONLY its own region: no extra barrier needed.
    #pragma unroll
    for (int j3 = 0; j3 < 3; ++j3) {
        const bf16x8 bfx = *(const bf16x8*)&xb[(((j3 + 3) * 4 + quad) * NSAMP + m16) * 8];
        #pragma unroll
        for (int g = 0; g < 4; ++g) {
            const f32x4 a = __builtin_amdgcn_mfma_f32_16x16x32_bf16(
                wf[g][4], bfx, f32x4{0.f, 0.f, 0.f, 0.f}, 0, 0, 0);
            float4 e;
            e.x = __builtin_amdgcn_exp2f(a[0]);
            e.y = __builtin_amdgcn_exp2f(a[1]);
            e.z = __builtin_amdgcn_exp2f(a[2]);
            e.w = __builtin_amdgcn_exp2f(a[3]);
            *(float4*)&Exs[((((j3 * 4 + g) * 8 + w) * 64) + quad * 16 + m16) * 4] = e;
        }
    }

    float mh[4] = {-1e30f, -1e30f, -1e30f, -1e30f};
    const int kslot = w * 2 + (quad >> 1);
    float c_slots[NSLOT][4];    // f32 c state, lane-private, static idx

    // shared pointwise tail: (u,q,v,qo,cprev) -> cn,h ; publish if sl>=0
    auto pw_tail = [&](const float (&u4)[4], const float (&q4)[4],
                       const float (&v4)[4], const float (&qo4)[4],
                       const float (&cp4)[4], int sl) {
        float hn4[4];
        #pragma unroll
        for (int r = 0; r < 4; ++r) {
            const float uv  = u4[r] * v4[r];
            const float num = fmaf(q4[r], v4[r] - 2.0f, cp4[r] * uv);
            const float cn  = num * __builtin_amdgcn_rcpf(q4[r] * uv);
            const float wt  = 1.0f + __builtin_amdgcn_exp2f(TWOL2E * cn);
            const float h   = (wt - 2.0f) * __builtin_amdgcn_rcpf(qo4[r] * wt);
            hn4[r] = h;
            mh[r] = fmaxf(mh[r], h);
            if (sl >= 0) c_slots[sl][r] = cn;
        }
        if (sl >= 0) {
            uint2 hw; hw.x = pk2(hn4[0], hn4[1]); hw.y = pk2(hn4[2], hn4[3]);
            *(uint2*)&hs[((sl * 16 + kslot) * NSAMP + m16) * 8 + (quad & 1) * 4] = hw;
        }
    };

    // ---- main loop: per level, per parent-group ----
    #pragma unroll
    for (int d = 1; d <= 6; ++d) {
        __syncthreads();
        const int gBeg = PL3.lvlG[d];
        const int gEnd = PL3.lvlG[d + 1];
        #pragma unroll
        for (int gi = gBeg; gi < gEnd; ++gi) {
            const int ps = PL3.gps[gi];
            // -- zh chain (16 MFMA) + Eh = exp2(zh) + cprev (regs) --
            f32x4 zh[4];
            float Eh[4][4];
            float cp4[4];
            #pragma unroll
            for (int g2 = 0; g2 < 4; ++g2) zh[g2] = f32x4{0.f, 0.f, 0.f, 0.f};
            if (ps >= 0) {
                #pragma unroll
                for (int q = 0; q < 4; ++q) {
                    const bf16x8 bh = *(const bf16x8*)
                        &hs[((ps * 16 + q * 4 + quad) * NSAMP + m16) * 8];
                    #pragma unroll
                    for (int g2 = 0; g2 < 4; ++g2)
                        zh[g2] = __builtin_amdgcn_mfma_f32_16x16x32_bf16(
                            wf[g2][q], bh, zh[g2], 0, 0, 0);
                }
                #pragma unroll
                for (int g2 = 0; g2 < 4; ++g2)
                    #pragma unroll
                    for (int r = 0; r < 4; ++r)
                        Eh[g2][r] = __builtin_amdgcn_exp2f(zh[g2][r]);
                #pragma unroll
                for (int r = 0; r < 4; ++r) cp4[r] = c_slots[ps][r];
            } else {
                #pragma unroll
                for (int g2 = 0; g2 < 4; ++g2)
                    #pragma unroll
                    for (int r = 0; r < 4; ++r) Eh[g2][r] = 1.0f;
                #pragma unroll
                for (int r = 0; r < 4; ++r) cp4[r] = 0.0f;
            }
            // -- children --
            #pragma unroll
            for (int ci = PL3.gbeg[gi]; ci < PL3.gbeg[gi + 1]; ++ci) {
                if (PL3.ch[ci].bar) __syncthreads();   // recycle barrier (constexpr)
                const int jo = PL3.ch[ci].jo;
                float u4[4], q4[4], v4[4], qo4[4];
                if (jo >= 3) {
                    // Ex path: sigmoid args via Eh*Ex (4 ds_read_b128 + 16 FMA)
                    const int j3 = jo - 3;
                    const float4 e0 = *(const float4*)
                        &Exs[((((j3 * 4 + 0) * 8 + w) * 64) + quad * 16 + m16) * 4];
                    const float4 e1 = *(const float4*)
                        &Exs[((((j3 * 4 + 1) * 8 + w) * 64) + quad * 16 + m16) * 4];
                    const float4 e2 = *(const float4*)
                        &Exs[((((j3 * 4 + 2) * 8 + w) * 64) + quad * 16 + m16) * 4];
                    const float4 e3 = *(const float4*)
                        &Exs[((((j3 * 4 + 3) * 8 + w) * 64) + quad * 16 + m16) * 4];
                    const float ex0[4] = {e0.x, e0.y, e0.z, e0.w};
                    const float ex1[4] = {e1.x, e1.y, e1.z, e1.w};
                    const float ex2[4] = {e2.x, e2.y, e2.z, e2.w};
                    const float ex3[4] = {e3.x, e3.y, e3.z, e3.w};
                    #pragma unroll
                    for (int r = 0; r < 4; ++r) {
                        u4[r]  = fmaf(Eh[0][r], ex0[r], 1.0f);
                        q4[r]  = fmaf(Eh[1][r], ex1[r], 1.0f);
                        v4[r]  = fmaf(Eh[2][r], ex2[r], 1.0f);
                        qo4[r] = fmaf(Eh[3][r], ex3[r], 1.0f);
                    }
                } else {
                    // classic path: x-MFMA with C=zh, then exp2 per gate
                    const bf16x8 bfx = *(const bf16x8*)
                        &xb[((jo * 4 + quad) * NSAMP + m16) * 8];
                    f32x4 acc[4];
                    #pragma unroll
                    for (int g2 = 0; g2 < 4; ++g2)
                        acc[g2] = __builtin_amdgcn_mfma_f32_16x16x32_bf16(
                            wf[g2][4], bfx, zh[g2], 0, 0, 0);
                    #pragma unroll
                    for (int r = 0; r < 4; ++r) {
                        u4[r]  = 1.0f + __builtin_amdgcn_exp2f(acc[0][r]);
                        q4[r]  = 1.0f + __builtin_amdgcn_exp2f(acc[1][r]);
                        v4[r]  = 1.0f + __builtin_amdgcn_exp2f(acc[2][r]);
                        qo4[r] = 1.0f + __builtin_amdgcn_exp2f(acc[3][r]);
                    }
                }
                pw_tail(u4, q4, v4, qo4, cp4, PL3.ch[ci].sl);
            }
        }
    }

    __syncthreads();   // pools dead; reuse hs for epilogue
    {
        float4 v; v.x = mh[0]; v.y = mh[1]; v.z = mh[2]; v.w = mh[3];
        *(float4*)&s_maxh[m16 * HDIM + w * 16 + quad * 4] = v;
    }
    __syncthreads();

    // ---- FC1: f = t&255, sample half t>>8 (8 samples each) ----
    {
        const int f  = t & 255;
        const int sh = t >> 8;
        float a1[8];
        #pragma unroll
        for (int s = 0; s < 8; ++s) a1[s] = fc1_b[f];
        for (int k4 = 0; k4 < HDIM / 4; ++k4) {
            const float4 wv = *(const float4*)&fc1_W[f * HDIM + k4 * 4];
            #pragma unroll
            for (int s = 0; s < 8; ++s) {
                const float4 h4 = *(const float4*)&s_maxh[(sh * 8 + s) * HDIM + k4 * 4];
                a1[s] += wv.x * h4.x + wv.y * h4.y + wv.z * h4.z + wv.w * h4.w;
            }
        }
        #pragma unroll
        for (int s = 0; s < 8; ++s)
            s_fc1[(sh * 8 + s) * 256 + f] = fmaxf(a1[s], 0.0f);
    }
    __syncthreads();

    if (t < NSAMP * 10) {
        const int s = t / 10, a = t % 10;
        float acc2 = fc2_b[a];
        for (int f4 = 0; f4 < 256 / 4; ++f4) {
            const float4 wv = *(const float4*)&fc2_W[a * 256 + f4 * 4];
            const float4 v  = *(const float4*)&s_fc1[s * 256 + f4 * 4];
            acc2 += wv.x * v.x + wv.y * v.y + wv.z * v.z + wv.w * v.w;
        }
        s_logit[s * 10 + a] = acc2;
    }
    __syncthreads();

    if (t < NSAMP) {
        float m = -1e30f;
        #pragma unroll
        for (int a = 0; a < 10; ++a) m = fmaxf(m, s_logit[t * 10 + a]);
        float sum = 0.0f;
        #pragma unroll
        for (int a = 0; a < 10; ++a) sum += __expf(s_logit[t * 10 + a] - m);
        const float lse = m + __logf(sum);
        #pragma unroll
        for (int a = 0; a < 10; ++a)
            out[(s_base + t) * 10 + a] = s_logit[t * 10 + a] - lse;
    }
}

extern "C" void kernel_launch(void* const* d_in, const int* in_sizes, int n_in,
                              void* d_out, int out_size, void* d_ws, size_t ws_size,
                              hipStream_t stream)
{
    (void)d_ws; (void)ws_size; (void)n_in; (void)out_size;

    const float* x   = (const float*)d_in[0];
    const float* Wih = (const float*)d_in[1];
    const float* Whh = (const float*)d_in[2];
    const float* bih = (const float*)d_in[3];
    const float* bhh = (const float*)d_in[4];
    const float* f1w = (const float*)d_in[5];
    const float* f1b = (const float*)d_in[6];
    const float* f2w = (const float*)d_in[7];
    const float* f2b = (const float*)d_in[8];

    const int mb = in_sizes[0] / (NOBJ * DDIM);   // 8192
    dim3 grid(mb / NSAMP), block(BLOCK);
    subset_lstm_skew_kernel<<<grid, block, 0, stream>>>(
        x, Wih, Whh, bih, bhh, f1w, f1b, f2w, f2b, (float*)d_out);
}

// Round 7
// 187.352 us; speedup vs baseline: 2.1121x; 1.0165x over previous
//
#include <hip/hip_runtime.h>
#include <hip/hip_bf16.h>

#define BLOCK   512     // 8 waves; wave w owns channels w*16..w*16+15, all 4 gates
#define NSAMP   16
#define HDIM    128
#define DDIM    16
#define NOBJ    6
#define NSLOT   14

typedef __attribute__((ext_vector_type(8))) short bf16x8;
typedef __attribute__((ext_vector_type(4))) float f32x4;

constexpr int pc6(int m)  { int c = 0; for (int i = 0; i < 6; ++i) c += (m >> i) & 1; return c; }
constexpr int msb6(int m) { int b = -1; for (int i = 0; i < 6; ++i) if (m & (1 << i)) b = i; return b; }

// ---- Grouped plan (verified R4): children grouped by PARENT so W_hh*h_P (zh)
// is computed ONCE per parent. Parent slot freeable once zh/c read (cached in
// regs); allocator inserts recycle barriers when the 14-slot pool is full.
struct GChild { int jo, sl; bool bar; };
struct Plan3 {
    int    gps [32];    // parent slot per group (-1 for the root pseudo-parent)
    int    gbeg[33];    // child range per group: [gbeg[g], gbeg[g+1])
    GChild ch  [63];
    int    lvlG[8];     // group range per level d: [lvlG[d], lvlG[d+1])
    bool   ok;
};
constexpr Plan3 make_plan3() {
    Plan3 P{};
    P.ok = true;
    int  slotOf[64] = {};
    bool busy[NSLOT] = {};
    int  pendingFree[NSLOT] = {};   // parent slots read, freeable at next barrier
    int  npend = 0;
    int  g = 0, cidx = 0;
    for (int d = 1; d <= 6; ++d) {
        P.lvlG[d] = g;
        for (int Pm = 0; Pm < 64; ++Pm) {
            if (pc6(Pm) != d - 1) continue;
            if (Pm != 0 && msb6(Pm) == 5) continue;      // leaves have no children
            P.gps[g]  = (Pm == 0) ? -1 : slotOf[Pm];
            P.gbeg[g] = cidx;
            if (Pm != 0) pendingFree[npend++] = slotOf[Pm];   // zh/c read at group start
            const int j0 = (Pm == 0) ? 0 : msb6(Pm) + 1;
            for (int j = j0; j <= 5; ++j) {
                const int M = Pm | (1 << j);
                P.ch[cidx].jo  = j;
                P.ch[cidx].bar = false;
                int sl = -1;
                if (j < 5) {
                    int fs = -1;
                    for (int s = 0; s < NSLOT; ++s) if (!busy[s]) { fs = s; break; }
                    if (fs < 0) {   // recycle barrier: free all pending parents
                        P.ch[cidx].bar = true;
                        if (npend == 0) P.ok = false;
                        for (int i = 0; i < npend; ++i) busy[pendingFree[i]] = false;
                        npend = 0;
                        for (int s = 0; s < NSLOT; ++s) if (!busy[s]) { fs = s; break; }
                        if (fs < 0) P.ok = false;
                    }
                    if (fs >= 0) { busy[fs] = true; slotOf[M] = fs; sl = fs; }
                }
                P.ch[cidx].sl = sl;
                ++cidx;
            }
            ++g;
        }
        // level-end barrier frees all parents read during this level
        for (int i = 0; i < npend; ++i) busy[pendingFree[i]] = false;
        npend = 0;
    }
    P.lvlG[7] = g;
    P.gbeg[g] = cidx;
    if (g != 32 || cidx != 63) P.ok = false;
    return P;
}
constexpr Plan3 PL3 = make_plan3();
static_assert(PL3.ok, "plan allocation failed");
static_assert(PL3.lvlG[7] == 32, "32 groups expected");
static_assert(PL3.gbeg[32] == 63, "63 children expected");

#define LOG2E   1.44269504f
#define TWOL2E  2.88539008f
#define SLOT_SH 2048            // shorts per slot (4 KB), h pool

__device__ __forceinline__ unsigned short f2bf(float x) {
    union { float f; unsigned int u; } a; a.f = x;
    unsigned int r = (a.u + 0x7FFFu + ((a.u >> 16) & 1u)) >> 16;
    return (unsigned short)r;
}
__device__ __forceinline__ unsigned pk2(float a, float b) {
    union { __hip_bfloat162 h; unsigned u; } z;
    z.h = __float22bfloat162_rn(float2{a, b});
    return z.u;
}

// h pool: hs[((slot*16 + kslot)*NSAMP + n)*8 + j] = h[ch = kslot*8+j][sample n]
//   B-frag chunk q, lane (quad,m16): kslot = q*4+quad -> 16B-aligned ds_read_b128
//   wave w writes ch = w*16+quad*4+r at kslot = w*2+(quad>>1), j = (quad&1)*4+r
// c state: f32 in registers c_slots[NSLOT][4], statically indexed (R6-verified,
//   VGPR_Count=128, zero scratch).
// R7: LDS cut to 62 KB (hs+xb only; Ex pool deleted — R6 proved it neutral,
//   and its float4 reads tripled bank conflicts).  62 KB -> 2 blocks/CU ->
//   16 waves/CU = 4 waves/SIMD.  Occupancy doubling is the entire bet; the
//   R4-R6 invariant (138 us across 3 different instruction mixes) shows the
//   kernel is latency-bound with only 2 barrier-locked waves/SIMD.

__global__ __launch_bounds__(BLOCK)
__attribute__((amdgpu_waves_per_eu(2, 4)))   // only attested no-spill envelope
void subset_lstm_skew_kernel(
    const float* __restrict__ x_input,
    const float* __restrict__ W_ih,
    const float* __restrict__ W_hh,
    const float* __restrict__ b_ih,
    const float* __restrict__ b_hh,
    const float* __restrict__ fc1_W,
    const float* __restrict__ fc1_b,
    const float* __restrict__ fc2_W,
    const float* __restrict__ fc2_b,
    float* __restrict__ out)
{
    __shared__ __align__(16) unsigned short hs [NSLOT * SLOT_SH];       // 56 KB
    __shared__ __align__(16) unsigned short xb[NOBJ * 4 * NSAMP * 8];   // 6 KB
    float* s_maxh  = (float*)hs;                 // 8 KB  (post-LSTM alias)
    float* s_fc1   = (float*)(hs + 4096);        // 16 KB (post-LSTM alias)
    float* s_logit = (float*)xb;

    const int t      = threadIdx.x;
    const int w      = t >> 6;
    const int lane   = t & 63;
    const int quad   = lane >> 4;
    const int m16    = lane & 15;
    const int s_base = blockIdx.x * NSAMP;

    // ---- x B-chunks: xb[obj][quad'][n][j]; quad2 j0 = 1.0 (bias lane), quad3 zero ----
    for (int idx = t; idx < NOBJ * 4 * NSAMP * 8; idx += BLOCK) {
        const int j = idx & 7, n = (idx >> 3) & 15, q = (idx >> 7) & 3, obj = idx >> 9;
        float v;
        if (q < 2) v = x_input[(s_base + n) * (NOBJ * DDIM) + obj * DDIM + q * 8 + j];
        else       v = (q == 2 && j == 0) ? 1.0f : 0.0f;
        xb[idx] = f2bf(v);
    }

    // ---- persistent A-frags wf[gate][chunk], PRE-SCALED (verified R8-R13) ----
    bf16x8 wf[4][5];
    #pragma unroll
    for (int g = 0; g < 4; ++g) {
        const float sc = (g == 2) ? TWOL2E : -LOG2E;
        const int grow = g * HDIM + w * 16 + m16;
        const float* whr = W_hh + grow * HDIM;
        const float* wir = W_ih + grow * DDIM;
        #pragma unroll
        for (int q = 0; q < 4; ++q) {
            union { unsigned short u[8]; bf16x8 v; } pk;
            #pragma unroll
            for (int j = 0; j < 8; ++j)
                pk.u[j] = f2bf(sc * whr[q * 32 + quad * 8 + j]);
            wf[g][q] = pk.v;
        }
        {
            union { unsigned short u[8]; bf16x8 v; } pk;
            #pragma unroll
            for (int j = 0; j < 8; ++j) {
                float v = 0.0f;
                if (quad < 2) v = sc * wir[quad * 8 + j];
                else if (quad == 2 && j == 0) v = sc * (b_ih[grow] + b_hh[grow]);
                pk.u[j] = f2bf(v);
            }
            wf[g][4] = pk.v;
        }
    }

    float mh[4] = {-1e30f, -1e30f, -1e30f, -1e30f};
    const int kslot = w * 2 + (quad >> 1);
    float c_slots[NSLOT][4];    // f32 c state, lane-private, static idx

    // shared pointwise tail: (u,q,v,qo,cprev) -> cn,h ; publish if sl>=0
    auto pw_tail = [&](const float (&u4)[4], const float (&q4)[4],
                       const float (&v4)[4], const float (&qo4)[4],
                       const float (&cp4)[4], int sl) {
        float hn4[4];
        #pragma unroll
        for (int r = 0; r < 4; ++r) {
            const float uv  = u4[r] * v4[r];
            const float num = fmaf(q4[r], v4[r] - 2.0f, cp4[r] * uv);
            const float cn  = num * __builtin_amdgcn_rcpf(q4[r] * uv);
            const float wt  = 1.0f + __builtin_amdgcn_exp2f(TWOL2E * cn);
            const float h   = (wt - 2.0f) * __builtin_amdgcn_rcpf(qo4[r] * wt);
            hn4[r] = h;
            mh[r] = fmaxf(mh[r], h);
            if (sl >= 0) c_slots[sl][r] = cn;
        }
        if (sl >= 0) {
            uint2 hw; hw.x = pk2(hn4[0], hn4[1]); hw.y = pk2(hn4[2], hn4[3]);
            *(uint2*)&hs[((sl * 16 + kslot) * NSAMP + m16) * 8 + (quad & 1) * 4] = hw;
        }
    };

    // ---- main loop: per level, per parent-group ----
    #pragma unroll
    for (int d = 1; d <= 6; ++d) {
        __syncthreads();
        const int gBeg = PL3.lvlG[d];
        const int gEnd = PL3.lvlG[d + 1];
        #pragma unroll
        for (int gi = gBeg; gi < gEnd; ++gi) {
            const int ps = PL3.gps[gi];
            // -- zh chain (16 MFMA) + cprev (regs) --
            f32x4 zh[4];
            float cp4[4];
            #pragma unroll
            for (int g2 = 0; g2 < 4; ++g2) zh[g2] = f32x4{0.f, 0.f, 0.f, 0.f};
            if (ps >= 0) {
                #pragma unroll
                for (int q = 0; q < 4; ++q) {
                    const bf16x8 bh = *(const bf16x8*)
                        &hs[((ps * 16 + q * 4 + quad) * NSAMP + m16) * 8];
                    #pragma unroll
                    for (int g2 = 0; g2 < 4; ++g2)
                        zh[g2] = __builtin_amdgcn_mfma_f32_16x16x32_bf16(
                            wf[g2][q], bh, zh[g2], 0, 0, 0);
                }
                #pragma unroll
                for (int r = 0; r < 4; ++r) cp4[r] = c_slots[ps][r];
            } else {
                #pragma unroll
                for (int r = 0; r < 4; ++r) cp4[r] = 0.0f;
            }
            // -- children: x-MFMA with C=zh, then pointwise --
            #pragma unroll
            for (int ci = PL3.gbeg[gi]; ci < PL3.gbeg[gi + 1]; ++ci) {
                if (PL3.ch[ci].bar) __syncthreads();   // recycle barrier (constexpr)
                const int jo = PL3.ch[ci].jo;
                const bf16x8 bfx = *(const bf16x8*)
                    &xb[((jo * 4 + quad) * NSAMP + m16) * 8];
                f32x4 acc[4];
                #pragma unroll
                for (int g2 = 0; g2 < 4; ++g2)
                    acc[g2] = __builtin_amdgcn_mfma_f32_16x16x32_bf16(
                        wf[g2][4], bfx, zh[g2], 0, 0, 0);
                float u4[4], q4[4], v4[4], qo4[4];
                #pragma unroll
                for (int r = 0; r < 4; ++r) {
                    u4[r]  = 1.0f + __builtin_amdgcn_exp2f(acc[0][r]);
                    q4[r]  = 1.0f + __builtin_amdgcn_exp2f(acc[1][r]);
                    v4[r]  = 1.0f + __builtin_amdgcn_exp2f(acc[2][r]);
                    qo4[r] = 1.0f + __builtin_amdgcn_exp2f(acc[3][r]);
                }
                pw_tail(u4, q4, v4, qo4, cp4, PL3.ch[ci].sl);
            }
        }
    }

    __syncthreads();   // pools dead; reuse hs for epilogue
    {
        float4 v; v.x = mh[0]; v.y = mh[1]; v.z = mh[2]; v.w = mh[3];
        *(float4*)&s_maxh[m16 * HDIM + w * 16 + quad * 4] = v;
    }
    __syncthreads();

    // ---- FC1: f = t&255, sample half t>>8 (8 samples each) ----
    {
        const int f  = t & 255;
        const int sh = t >> 8;
        float a1[8];
        #pragma unroll
        for (int s = 0; s < 8; ++s) a1[s] = fc1_b[f];
        for (int k4 = 0; k4 < HDIM / 4; ++k4) {
            const float4 wv = *(const float4*)&fc1_W[f * HDIM + k4 * 4];
            #pragma unroll
            for (int s = 0; s < 8; ++s) {
                const float4 h4 = *(const float4*)&s_maxh[(sh * 8 + s) * HDIM + k4 * 4];
                a1[s] += wv.x * h4.x + wv.y * h4.y + wv.z * h4.z + wv.w * h4.w;
            }
        }
        #pragma unroll
        for (int s = 0; s < 8; ++s)
            s_fc1[(sh * 8 + s) * 256 + f] = fmaxf(a1[s], 0.0f);
    }
    __syncthreads();

    if (t < NSAMP * 10) {
        const int s = t / 10, a = t % 10;
        float acc2 = fc2_b[a];
        for (int f4 = 0; f4 < 256 / 4; ++f4) {
            const float4 wv = *(const float4*)&fc2_W[a * 256 + f4 * 4];
            const float4 v  = *(const float4*)&s_fc1[s * 256 + f4 * 4];
            acc2 += wv.x * v.x + wv.y * v.y + wv.z * v.z + wv.w * v.w;
        }
        s_logit[s * 10 + a] = acc2;
    }
    __syncthreads();

    if (t < NSAMP) {
        float m = -1e30f;
        #pragma unroll
        for (int a = 0; a < 10; ++a) m = fmaxf(m, s_logit[t * 10 + a]);
        float sum = 0.0f;
        #pragma unroll
        for (int a = 0; a < 10; ++a) sum += __expf(s_logit[t * 10 + a] - m);
        const float lse = m + __logf(sum);
        #pragma unroll
        for (int a = 0; a < 10; ++a)
            out[(s_base + t) * 10 + a] = s_logit[t * 10 + a] - lse;
    }
}

extern "C" void kernel_launch(void* const* d_in, const int* in_sizes, int n_in,
                              void* d_out, int out_size, void* d_ws, size_t ws_size,
                              hipStream_t stream)
{
    (void)d_ws; (void)ws_size; (void)n_in; (void)out_size;

    const float* x   = (const float*)d_in[0];
    const float* Wih = (const float*)d_in[1];
    const float* Whh = (const float*)d_in[2];
    const float* bih = (const float*)d_in[3];
    const float* bhh = (const float*)d_in[4];
    const float* f1w = (const float*)d_in[5];
    const float* f1b = (const float*)d_in[6];
    const float* f2w = (const float*)d_in[7];
    const float* f2b = (const float*)d_in[8];

    const int mb = in_sizes[0] / (NOBJ * DDIM);   // 8192
    dim3 grid(mb / NSAMP), block(BLOCK);          // 512 blocks = 2 resident/CU
    subset_lstm_skew_kernel<<<grid, block, 0, stream>>>(
        x, Wih, Whh, bih, bhh, f1w, f1b, f2w, f2b, (float*)d_out);
}